// Round 1
// baseline (44649.924 us; speedup 1.0000x reference)
//
#include <hip/hip_runtime.h>
#include <math.h>

#define NB 8
#define DDIM 768
#define NHEAD 12
#define NDEPTH 12
#define HDIM 64
#define GRIDW 24
#define NL0 576
#define NL 577
#define NHID 3072
#define MROWS (NB*NL)   // 4616
#define EPSV 1e-5f

// ---------------- im2col: x[B,3,384,384] -> patches[4608, 768] ----------------
__global__ void im2col_k(const float* __restrict__ x, float* __restrict__ p) {
    int idx = blockIdx.x * 256 + threadIdx.x;   // total 4608*768 = 3538944, exact grid
    int row = idx / 768, col = idx - row * 768;
    int b = row / NL0, pi = row - b * NL0;
    int gy = pi / GRIDW, gx = pi - gy * GRIDW;
    int c = col >> 8, r = col & 255;
    int py = r >> 4, px = r & 15;
    p[idx] = x[(((long)(b * 3 + c) * 384) + gy * 16 + py) * 384 + gx * 16 + px];
}

// ---------------- CLS token rows ----------------
__global__ void cls_k(const float* __restrict__ cls, float* __restrict__ t) {
    t[(long)blockIdx.x * NL * DDIM + threadIdx.x] = cls[threadIdx.x];
}

// ---------------- RoPE tables: [576, 64] sin/cos ----------------
__global__ void rope_k(float* __restrict__ sin_t, float* __restrict__ cos_t) {
    int pos = blockIdx.x;          // 0..575
    int d = threadIdx.x;           // 0..63
    int gy = pos / GRIDW, gx = pos - gy * GRIDW;
    int j = d >> 1;                // 0..31
    float ang;
    if (j < 16) ang = (float)gy * powf(10000.f, -(float)j / 16.f);
    else        ang = (float)gx * powf(10000.f, -(float)(j - 16) / 16.f);
    sin_t[pos * 64 + d] = sinf(ang);
    cos_t[pos * 64 + d] = cosf(ang);
}

// ---------------- LayerNorm over D=768, one block per row ----------------
__global__ __launch_bounds__(256) void ln_k(const float* __restrict__ in,
                                            const float* __restrict__ sc,
                                            const float* __restrict__ bi,
                                            float* __restrict__ out,
                                            long in_rstride, long out_rstride) {
    int row = blockIdx.x;
    const float* ip = in + (long)row * in_rstride;
    float x[3];
    float s = 0.f, s2 = 0.f;
    #pragma unroll
    for (int i = 0; i < 3; ++i) {
        x[i] = ip[threadIdx.x + i * 256];
        s += x[i]; s2 += x[i] * x[i];
    }
    __shared__ float red0[256], red1[256];
    red0[threadIdx.x] = s; red1[threadIdx.x] = s2;
    __syncthreads();
    for (int off = 128; off; off >>= 1) {
        if (threadIdx.x < off) {
            red0[threadIdx.x] += red0[threadIdx.x + off];
            red1[threadIdx.x] += red1[threadIdx.x + off];
        }
        __syncthreads();
    }
    float mean = red0[0] * (1.f / 768.f);
    float var  = red1[0] * (1.f / 768.f) - mean * mean;
    float inv = rsqrtf(var + EPSV);
    float* op = out + (long)row * out_rstride;
    #pragma unroll
    for (int i = 0; i < 3; ++i) {
        int c = threadIdx.x + i * 256;
        op[c] = (x[i] - mean) * inv * sc[c] + bi[c];
    }
}

// ---------------- generic fp32 GEMM: C[M,N] = A[M,K] @ W[N,K]^T (+epilogue) ----
// flags: 1=bias, 2=resid(add, indexed by output row), 4=gelu(exact), 8=row remap 576->577 (+1, skip CLS)
__global__ __launch_bounds__(256) void gemm_k(const float* __restrict__ A,
                                              const float* __restrict__ W,
                                              const float* __restrict__ bias,
                                              const float* __restrict__ resid,
                                              float* __restrict__ C,
                                              int M, int N, int K, int flags) {
    __shared__ float As[32][33];
    __shared__ float Ws[32][33];
    int tid = threadIdx.x;
    int tx = tid & 31, ty = tid >> 5;
    int n0 = blockIdx.x * 32, m0 = blockIdx.y * 32;
    float acc[4] = {0.f, 0.f, 0.f, 0.f};
    for (int kt = 0; kt < K; kt += 32) {
        #pragma unroll
        for (int i = 0; i < 4; ++i) {
            int e = tid + i * 256;
            int r = e >> 5, c = e & 31;
            int gr = m0 + r;
            As[r][c] = (gr < M) ? A[(long)gr * K + kt + c] : 0.f;
            Ws[c][r] = W[(long)(n0 + r) * K + kt + c];
        }
        __syncthreads();
        #pragma unroll
        for (int kk = 0; kk < 32; ++kk) {
            float w = Ws[kk][tx];
            #pragma unroll
            for (int i = 0; i < 4; ++i) acc[i] = fmaf(As[ty + 8 * i][kk], w, acc[i]);
        }
        __syncthreads();
    }
    int col = n0 + tx;
    #pragma unroll
    for (int i = 0; i < 4; ++i) {
        int row = m0 + ty + 8 * i;
        if (row >= M) continue;
        float val = acc[i];
        if (flags & 1) val += bias[col];
        if (flags & 4) val = 0.5f * val * (1.f + erff(val * 0.70710678118654752f));
        long orow = row;
        if (flags & 8) orow = (long)(row / NL0) * NL + 1 + (row % NL0);
        if (flags & 2) val += resid[orow * N + col];
        C[orow * N + col] = val;
    }
}

// ---------------- qkv[B*L, 3*768] -> q/k/v[B,H,L,64] with RoPE on q,k (patch tokens) ----
__global__ void qkvrope_k(const float* __restrict__ qkv,
                          const float* __restrict__ sin_t, const float* __restrict__ cos_t,
                          float* __restrict__ q, float* __restrict__ k, float* __restrict__ v) {
    int blk = blockIdx.x;                // B*H*L blocks
    int l = blk % NL; int bh = blk / NL;
    int h = bh % NHEAD; int b = bh / NHEAD;
    int d = threadIdx.x;                 // 0..63
    long base_in = ((long)(b * NL + l)) * (3 * DDIM) + h * HDIM + d;
    float qv = qkv[base_in];
    float kv = qkv[base_in + DDIM];
    float vv = qkv[base_in + 2 * DDIM];
    if (l > 0) {                          // uniform across the single wave
        int pos = l - 1;
        float cs = cos_t[pos * 64 + d], sn = sin_t[pos * 64 + d];
        float qo = __shfl_xor(qv, 32);
        float ko = __shfl_xor(kv, 32);
        float qrh = (d < 32) ? -qo : qo;
        float krh = (d < 32) ? -ko : ko;
        qv = qv * cs + qrh * sn;
        kv = kv * cs + krh * sn;
    }
    long oidx = ((long)bh * NL + l) * HDIM + d;
    q[oidx] = qv; k[oidx] = kv; v[oidx] = vv;
}

// ---------------- attention: one wave per query row, scores in LDS ----------------
__global__ __launch_bounds__(256) void attn_k(const float* __restrict__ q,
                                              const float* __restrict__ k,
                                              const float* __restrict__ v,
                                              float* __restrict__ o) {
    __shared__ float sc[4][608];
    __shared__ float qr[4][64];
    int wave = threadIdx.x >> 6, lane = threadIdx.x & 63;
    int row = blockIdx.x * 4 + wave;     // grid exact: 55392/4
    int bh = row / NL, qi = row - bh * NL;
    long base = (long)bh * NL * HDIM;
    qr[wave][lane] = q[base + (long)qi * HDIM + lane];
    __syncthreads();
    float lmax = -1e30f;
    for (int t0 = 0; t0 < 10; ++t0) {
        int kj = t0 * 64 + lane;
        if (kj < NL) {
            float s = 0.f;
            const float* kp = k + base + (long)kj * HDIM;
            #pragma unroll
            for (int d2 = 0; d2 < 64; ++d2) s = fmaf(qr[wave][d2], kp[d2], s);
            s *= 0.125f;
            sc[wave][kj] = s;
            lmax = fmaxf(lmax, s);
        }
    }
    #pragma unroll
    for (int off = 32; off; off >>= 1) lmax = fmaxf(lmax, __shfl_xor(lmax, off));
    float lsum = 0.f;
    for (int t0 = 0; t0 < 10; ++t0) {
        int kj = t0 * 64 + lane;
        if (kj < NL) {
            float e = __expf(sc[wave][kj] - lmax);
            sc[wave][kj] = e;
            lsum += e;
        }
    }
    #pragma unroll
    for (int off = 32; off; off >>= 1) lsum += __shfl_xor(lsum, off);
    float inv = 1.f / lsum;
    __syncthreads();
    float acc = 0.f;
    const float* vp = v + base + lane;
    for (int j = 0; j < NL; ++j) acc = fmaf(sc[wave][j], vp[(long)j * HDIM], acc);
    int b = bh / NHEAD, h = bh - b * NHEAD;
    o[((long)(b * NL + qi)) * DDIM + h * HDIM + lane] = acc * inv;
}

extern "C" void kernel_launch(void* const* d_in, const int* in_sizes, int n_in,
                              void* d_out, int out_size, void* d_ws, size_t ws_size,
                              hipStream_t stream) {
    const float* x       = (const float*)d_in[0];
    const float* patch_w = (const float*)d_in[1];
    const float* patch_b = (const float*)d_in[2];
    const float* cls     = (const float*)d_in[3];
    const float* ln1_s   = (const float*)d_in[4];
    const float* ln1_b   = (const float*)d_in[5];
    const float* qkv_w   = (const float*)d_in[6];
    const float* proj_w  = (const float*)d_in[7];
    const float* proj_b  = (const float*)d_in[8];
    const float* ln2_s   = (const float*)d_in[9];
    const float* ln2_b   = (const float*)d_in[10];
    const float* mlp_w1  = (const float*)d_in[11];
    const float* mlp_b1  = (const float*)d_in[12];
    const float* mlp_w2  = (const float*)d_in[13];
    const float* mlp_b2  = (const float*)d_in[14];
    const float* norm_s  = (const float*)d_in[15];
    const float* norm_b  = (const float*)d_in[16];

    float* ws = (float*)d_ws;
    const long SZ_T = (long)MROWS * DDIM;            // 3,545,088
    float* t     = ws;
    float* h     = t + SZ_T;
    float* q     = h + SZ_T;
    float* k     = q + SZ_T;
    float* v     = k + SZ_T;
    float* o     = v + SZ_T;
    float* big   = o + SZ_T;                          // 14,180,352 floats (shared: im2col / qkv / mlp-hid)
    float* sin_t = big + (long)MROWS * NHID;
    float* cos_t = sin_t + NL0 * HDIM;

    // RoPE tables
    hipLaunchKernelGGL(rope_k, dim3(NL0), dim3(64), 0, stream, sin_t, cos_t);
    // im2col
    hipLaunchKernelGGL(im2col_k, dim3((NB * NL0 * 768) / 256), dim3(256), 0, stream, x, big);
    // CLS rows
    hipLaunchKernelGGL(cls_k, dim3(NB), dim3(DDIM), 0, stream, cls, t);
    // patch embed GEMM -> t rows 1..576 per batch (flags: bias | remap)
    hipLaunchKernelGGL(gemm_k, dim3(DDIM / 32, (NB * NL0) / 32), dim3(256), 0, stream,
                       big, patch_w, patch_b, (const float*)nullptr, t,
                       NB * NL0, DDIM, 768, 1 | 8);

    for (int i = 0; i < NDEPTH; ++i) {
        hipLaunchKernelGGL(ln_k, dim3(MROWS), dim3(256), 0, stream,
                           t, ln1_s + i * DDIM, ln1_b + i * DDIM, h, (long)DDIM, (long)DDIM);
        hipLaunchKernelGGL(gemm_k, dim3((3 * DDIM) / 32, (MROWS + 31) / 32), dim3(256), 0, stream,
                           h, qkv_w + (long)i * 3 * DDIM * DDIM, (const float*)nullptr,
                           (const float*)nullptr, big, MROWS, 3 * DDIM, DDIM, 0);
        hipLaunchKernelGGL(qkvrope_k, dim3(NB * NHEAD * NL), dim3(64), 0, stream,
                           big, sin_t, cos_t, q, k, v);
        hipLaunchKernelGGL(attn_k, dim3(NB * NHEAD * NL / 4), dim3(256), 0, stream, q, k, v, o);
        hipLaunchKernelGGL(gemm_k, dim3(DDIM / 32, (MROWS + 31) / 32), dim3(256), 0, stream,
                           o, proj_w + (long)i * DDIM * DDIM, proj_b + i * DDIM, t, t,
                           MROWS, DDIM, DDIM, 1 | 2);
        hipLaunchKernelGGL(ln_k, dim3(MROWS), dim3(256), 0, stream,
                           t, ln2_s + i * DDIM, ln2_b + i * DDIM, h, (long)DDIM, (long)DDIM);
        hipLaunchKernelGGL(gemm_k, dim3(NHID / 32, (MROWS + 31) / 32), dim3(256), 0, stream,
                           h, mlp_w1 + (long)i * NHID * DDIM, mlp_b1 + i * NHID,
                           (const float*)nullptr, big, MROWS, NHID, DDIM, 1 | 4);
        hipLaunchKernelGGL(gemm_k, dim3(DDIM / 32, (MROWS + 31) / 32), dim3(256), 0, stream,
                           big, mlp_w2 + (long)i * DDIM * NHID, mlp_b2 + i * DDIM, t, t,
                           MROWS, DDIM, NHID, 1 | 2);
    }
    // final LN on the CLS row of each batch -> d_out [8, 768]
    hipLaunchKernelGGL(ln_k, dim3(NB), dim3(256), 0, stream,
                       t, norm_s, norm_b, (float*)d_out, (long)NL * DDIM, (long)DDIM);
}

// Round 2
// 14770.020 us; speedup vs baseline: 3.0230x; 3.0230x over previous
//
#include <hip/hip_runtime.h>
#include <math.h>

#define NB 8
#define DDIM 768
#define NHEAD 12
#define NDEPTH 12
#define HDIM 64
#define GRIDW 24
#define NL0 576
#define NL 577
#define NHID 3072
#define MROWS (NB*NL)     // 4616
#define MPAD 4736         // 37*128
#define EPSV 1e-5f

typedef unsigned short ushortT;
typedef __attribute__((ext_vector_type(8))) short bf16x8;
typedef __attribute__((ext_vector_type(4))) float f32x4;

__device__ __forceinline__ ushortT f2b(float f) {
    union { float f; unsigned u; } x; x.f = f;
    unsigned r = x.u + 0x7fffu + ((x.u >> 16) & 1u);
    return (ushortT)(r >> 16);
}

__device__ __forceinline__ void load_lds16(const void* g, void* l) {
    __builtin_amdgcn_global_load_lds((const __attribute__((address_space(1))) void*)g,
                                     (__attribute__((address_space(3))) void*)l, 16, 0, 0);
}

// ---------------- fp32 -> bf16 convert ----------------
__global__ void f2b_k(const float* __restrict__ in, ushortT* __restrict__ out, long n) {
    for (long i = ((long)blockIdx.x * 256 + threadIdx.x) * 4; i < n; i += (long)gridDim.x * 1024) {
        float4 v = *(const float4*)(in + i);
        ushortT o0 = f2b(v.x), o1 = f2b(v.y), o2 = f2b(v.z), o3 = f2b(v.w);
        ushort4 o; o.x = o0; o.y = o1; o.z = o2; o.w = o3;
        *(ushort4*)(out + i) = o;
    }
}

// ---------------- im2col -> bf16 patches[4608, 768] ----------------
__global__ void im2col_k(const float* __restrict__ x, ushortT* __restrict__ p) {
    for (long idx = (long)blockIdx.x * 256 + threadIdx.x; idx < (long)4608 * 768; idx += (long)gridDim.x * 256) {
        int row = (int)(idx / 768), col = (int)(idx - (long)row * 768);
        int b = row / NL0, pi = row - b * NL0;
        int gy = pi / GRIDW, gx = pi - gy * GRIDW;
        int c = col >> 8, r = col & 255;
        int py = r >> 4, px = r & 15;
        p[idx] = f2b(x[(((long)(b * 3 + c) * 384) + gy * 16 + py) * 384 + gx * 16 + px]);
    }
}

__global__ void cls_k(const float* __restrict__ cls, float* __restrict__ t) {
    t[(long)blockIdx.x * NL * DDIM + threadIdx.x] = cls[threadIdx.x];
}

__global__ void rope_k(float* __restrict__ sin_t, float* __restrict__ cos_t) {
    int pos = blockIdx.x, d = threadIdx.x;
    int gy = pos / GRIDW, gx = pos - gy * GRIDW;
    int j = d >> 1;
    float ang;
    if (j < 16) ang = (float)gy * powf(10000.f, -(float)j / 16.f);
    else        ang = (float)gx * powf(10000.f, -(float)(j - 16) / 16.f);
    sin_t[pos * 64 + d] = sinf(ang);
    cos_t[pos * 64 + d] = cosf(ang);
}

// ---------------- LayerNorm, one block per row; bf16 or fp32 out ----------------
__global__ __launch_bounds__(256) void ln_k(const float* __restrict__ in,
                                            const float* __restrict__ sc,
                                            const float* __restrict__ bi,
                                            float* __restrict__ outf,
                                            ushortT* __restrict__ outb,
                                            long in_rstride) {
    int row = blockIdx.x;
    const float* ip = in + (long)row * in_rstride;
    float x[3];
    float s = 0.f, s2 = 0.f;
    #pragma unroll
    for (int i = 0; i < 3; ++i) {
        x[i] = ip[threadIdx.x + i * 256];
        s += x[i]; s2 += x[i] * x[i];
    }
    __shared__ float red0[256], red1[256];
    red0[threadIdx.x] = s; red1[threadIdx.x] = s2;
    __syncthreads();
    for (int off = 128; off; off >>= 1) {
        if (threadIdx.x < off) {
            red0[threadIdx.x] += red0[threadIdx.x + off];
            red1[threadIdx.x] += red1[threadIdx.x + off];
        }
        __syncthreads();
    }
    float mean = red0[0] * (1.f / 768.f);
    float var  = red1[0] * (1.f / 768.f) - mean * mean;
    float inv = rsqrtf(var + EPSV);
    #pragma unroll
    for (int i = 0; i < 3; ++i) {
        int c = threadIdx.x + i * 256;
        float val = (x[i] - mean) * inv * sc[c] + bi[c];
        if (outb) outb[(long)row * 768 + c] = f2b(val);
        else      outf[(long)row * 768 + c] = val;
    }
}

// ---------------- bf16 MFMA GEMM: C[M,N] = A[M,K] @ W[N,K]^T ----------------
// flags: 1=bias 2=resid(f32) 4=gelu 8=remap(576->577) 16=store f32 32=store bf16
// M, N multiples of 128; K multiple of 64. No bounds checks.
__global__ __launch_bounds__(256) void gemm_bf16_k(const ushortT* __restrict__ A,
                                                   const ushortT* __restrict__ W,
                                                   const float* __restrict__ bias,
                                                   const float* __restrict__ resid,
                                                   float* __restrict__ Cf,
                                                   ushortT* __restrict__ Cb,
                                                   int N, int K, int flags) {
    __shared__ ushortT As[128 * 64];
    __shared__ ushortT Bs[128 * 64];
    int tid = threadIdx.x;
    int lane = tid & 63, wid = tid >> 6;
    int wm = wid >> 1, wn = wid & 1;
    int lr = lane & 15, lk = lane >> 4;
    int m0 = blockIdx.y * 128, n0 = blockIdx.x * 128;
    f32x4 acc[4][4] = {};
    for (int kt = 0; kt < K; kt += 64) {
        #pragma unroll
        for (int i = 0; i < 4; ++i) {
            int ch = i * 256 + tid;
            int r = ch >> 3, c = (ch & 7) * 8;
            load_lds16(A + (size_t)(m0 + r) * K + kt + c, As + ch * 8);
        }
        #pragma unroll
        for (int i = 0; i < 4; ++i) {
            int ch = i * 256 + tid;
            int r = ch >> 3, c = (ch & 7) * 8;
            load_lds16(W + (size_t)(n0 + r) * K + kt + c, Bs + ch * 8);
        }
        __syncthreads();
        #pragma unroll
        for (int ks = 0; ks < 2; ++ks) {
            bf16x8 aF[4], bF[4];
            #pragma unroll
            for (int mi = 0; mi < 4; ++mi)
                aF[mi] = *(const bf16x8*)&As[(wm * 64 + mi * 16 + lr) * 64 + ks * 32 + lk * 8];
            #pragma unroll
            for (int ni = 0; ni < 4; ++ni)
                bF[ni] = *(const bf16x8*)&Bs[(wn * 64 + ni * 16 + lr) * 64 + ks * 32 + lk * 8];
            #pragma unroll
            for (int mi = 0; mi < 4; ++mi)
                #pragma unroll
                for (int ni = 0; ni < 4; ++ni)
                    acc[mi][ni] = __builtin_amdgcn_mfma_f32_16x16x32_bf16(aF[mi], bF[ni], acc[mi][ni], 0, 0, 0);
        }
        __syncthreads();
    }
    // epilogue
    #pragma unroll
    for (int mi = 0; mi < 4; ++mi) {
        int rbase = m0 + wm * 64 + mi * 16 + (lane >> 4) * 4;
        #pragma unroll
        for (int ni = 0; ni < 4; ++ni) {
            int c = n0 + wn * 64 + ni * 16 + lr;
            float bv = (flags & 1) ? bias[c] : 0.f;
            #pragma unroll
            for (int r = 0; r < 4; ++r) {
                int row = rbase + r;
                float val = acc[mi][ni][r] + bv;
                if (flags & 4) val = 0.5f * val * (1.f + erff(val * 0.70710678118654752f));
                long orow = row;
                if (flags & 8) orow = (long)(row / NL0) * NL + 1 + (row % NL0);
                if (flags & 2) val += resid[orow * (long)N + c];
                if (flags & 16) Cf[orow * (long)N + c] = val;
                if (flags & 32) Cb[orow * (long)N + c] = f2b(val);
            }
        }
    }
}

// ---------------- qkv[B*L, 3*768](f32) -> q/k/v[B,H,L,64] with RoPE ----------------
__global__ __launch_bounds__(256) void qkvrope_k(const float* __restrict__ qkv,
                                                 const float* __restrict__ sin_t,
                                                 const float* __restrict__ cos_t,
                                                 float* __restrict__ q, float* __restrict__ k,
                                                 float* __restrict__ v) {
    int wave = threadIdx.x >> 6, lane = threadIdx.x & 63;
    for (int r4 = blockIdx.x; r4 < (NB * NHEAD * NL) / 4; r4 += gridDim.x) {
        int row = r4 * 4 + wave;
        int l = row % NL, bh = row / NL;
        int h = bh % NHEAD, b = bh / NHEAD;
        long base_in = ((long)(b * NL + l)) * (3 * DDIM) + h * HDIM + lane;
        float qv = qkv[base_in];
        float kv = qkv[base_in + DDIM];
        float vv = qkv[base_in + 2 * DDIM];
        if (l > 0) {
            int pos = l - 1;
            float cs = cos_t[pos * 64 + lane], sn = sin_t[pos * 64 + lane];
            float qo = __shfl_xor(qv, 32), ko = __shfl_xor(kv, 32);
            float qrh = (lane < 32) ? -qo : qo;
            float krh = (lane < 32) ? -ko : ko;
            qv = qv * cs + qrh * sn;
            kv = kv * cs + krh * sn;
        }
        long oidx = ((long)bh * NL + l) * HDIM + lane;
        q[oidx] = qv; k[oidx] = kv; v[oidx] = vv;
    }
}

// ---------------- attention: block = (bh, 4 q-rows); K tiles staged in LDS ----------------
#define QT 145   // ceil(577/4)
__global__ __launch_bounds__(256) void attn_k(const float* __restrict__ q,
                                              const float* __restrict__ k,
                                              const float* __restrict__ v,
                                              ushortT* __restrict__ o) {
    __shared__ float Ks[64][65];
    __shared__ float qr[4][64];
    __shared__ float sc[4][640];
    int tid = threadIdx.x;
    int wave = tid >> 6, lane = tid & 63;
    int bh = blockIdx.x / QT, qt = blockIdx.x % QT;
    int qi = qt * 4 + wave;
    bool qvalid = qi < NL;
    long base = (long)bh * NL * HDIM;
    if (qvalid) qr[wave][lane] = q[base + (long)qi * HDIM + lane];
    float lmax = -1e30f;
    for (int t0 = 0; t0 < 10; ++t0) {
        int kr = t0 * 64;
        __syncthreads();
        for (int e = tid; e < 4096; e += 256) {
            int r = e >> 6, c = e & 63;
            Ks[r][c] = (kr + r < NL) ? k[base + (long)(kr + r) * HDIM + c] : 0.f;
        }
        __syncthreads();
        if (qvalid && kr + lane < NL) {
            float s = 0.f;
            #pragma unroll
            for (int d2 = 0; d2 < 64; ++d2) s = fmaf(qr[wave][d2], Ks[lane][d2], s);
            s *= 0.125f;
            sc[wave][kr + lane] = s;
            lmax = fmaxf(lmax, s);
        }
    }
    #pragma unroll
    for (int off = 32; off; off >>= 1) lmax = fmaxf(lmax, __shfl_xor(lmax, off));
    float lsum = 0.f;
    for (int t0 = 0; t0 < 10; ++t0) {
        int kj = t0 * 64 + lane;
        if (qvalid && kj < NL) {
            float e = __expf(sc[wave][kj] - lmax);
            sc[wave][kj] = e;
            lsum += e;
        }
    }
    #pragma unroll
    for (int off = 32; off; off >>= 1) lsum += __shfl_xor(lsum, off);
    if (qvalid) {
        float inv = 1.f / lsum;
        float acc = 0.f;
        const float* vp = v + base + lane;
        for (int j = 0; j < NL; ++j) acc = fmaf(sc[wave][j], vp[(long)j * HDIM], acc);
        int b = bh / NHEAD, h = bh - b * NHEAD;
        o[((long)(b * NL + qi)) * DDIM + h * HDIM + lane] = f2b(acc * inv);
    }
}

extern "C" void kernel_launch(void* const* d_in, const int* in_sizes, int n_in,
                              void* d_out, int out_size, void* d_ws, size_t ws_size,
                              hipStream_t stream) {
    const float* x       = (const float*)d_in[0];
    const float* patch_w = (const float*)d_in[1];
    const float* patch_b = (const float*)d_in[2];
    const float* cls     = (const float*)d_in[3];
    const float* ln1_s   = (const float*)d_in[4];
    const float* ln1_b   = (const float*)d_in[5];
    const float* qkv_w   = (const float*)d_in[6];
    const float* proj_w  = (const float*)d_in[7];
    const float* proj_b  = (const float*)d_in[8];
    const float* ln2_s   = (const float*)d_in[9];
    const float* ln2_b   = (const float*)d_in[10];
    const float* mlp_w1  = (const float*)d_in[11];
    const float* mlp_b1  = (const float*)d_in[12];
    const float* mlp_w2  = (const float*)d_in[13];
    const float* mlp_b2  = (const float*)d_in[14];
    const float* norm_s  = (const float*)d_in[15];
    const float* norm_b  = (const float*)d_in[16];

    char* w = (char*)d_ws;
    float* t      = (float*)w;  w += (size_t)MPAD * DDIM * 4;
    float* qkvbuf = (float*)w;  w += (size_t)MPAD * 3 * DDIM * 4;
    float* qb     = (float*)w;  w += (size_t)96 * NL * HDIM * 4;
    float* kb     = (float*)w;  w += (size_t)96 * NL * HDIM * 4;
    float* vb     = (float*)w;  w += (size_t)96 * NL * HDIM * 4;
    float* sin_t  = (float*)w;  w += (size_t)NL0 * HDIM * 4;
    float* cos_t  = (float*)w;  w += (size_t)NL0 * HDIM * 4;
    ushortT* h_bf   = (ushortT*)w; w += (size_t)MPAD * DDIM * 2;
    ushortT* o_bf   = (ushortT*)w; w += (size_t)MPAD * DDIM * 2;
    ushortT* mlp_bf = (ushortT*)w; w += (size_t)MPAD * NHID * 2;
    ushortT* patches = mlp_bf;    // alias: disjoint lifetime (pre-loop only)
    ushortT* pw_bf  = (ushortT*)w; w += (size_t)DDIM * 768 * 2;
    ushortT* wq_bf  = (ushortT*)w; w += (size_t)3 * DDIM * DDIM * 2;
    ushortT* wp_bf  = (ushortT*)w; w += (size_t)DDIM * DDIM * 2;
    ushortT* w1_bf  = (ushortT*)w; w += (size_t)NHID * DDIM * 2;
    ushortT* w2_bf  = (ushortT*)w; w += (size_t)DDIM * NHID * 2;

    hipLaunchKernelGGL(rope_k, dim3(NL0), dim3(64), 0, stream, sin_t, cos_t);
    hipLaunchKernelGGL(im2col_k, dim3(2048), dim3(256), 0, stream, x, patches);
    hipLaunchKernelGGL(f2b_k, dim3(512), dim3(256), 0, stream, patch_w, pw_bf, (long)DDIM * 768);
    hipLaunchKernelGGL(cls_k, dim3(NB), dim3(DDIM), 0, stream, cls, t);
    // patch embed: [4608,768] @ [768,768]^T -> t rows (remap, bias, f32)
    hipLaunchKernelGGL(gemm_bf16_k, dim3(DDIM / 128, 4608 / 128), dim3(256), 0, stream,
                       patches, pw_bf, patch_b, (const float*)nullptr, t, (ushortT*)nullptr,
                       DDIM, 768, 1 | 8 | 16);

    for (int i = 0; i < NDEPTH; ++i) {
        hipLaunchKernelGGL(f2b_k, dim3(1024), dim3(256), 0, stream,
                           qkv_w + (size_t)i * 3 * DDIM * DDIM, wq_bf, (long)3 * DDIM * DDIM);
        hipLaunchKernelGGL(f2b_k, dim3(512), dim3(256), 0, stream,
                           proj_w + (size_t)i * DDIM * DDIM, wp_bf, (long)DDIM * DDIM);
        hipLaunchKernelGGL(f2b_k, dim3(1024), dim3(256), 0, stream,
                           mlp_w1 + (size_t)i * NHID * DDIM, w1_bf, (long)NHID * DDIM);
        hipLaunchKernelGGL(f2b_k, dim3(1024), dim3(256), 0, stream,
                           mlp_w2 + (size_t)i * DDIM * NHID, w2_bf, (long)DDIM * NHID);

        hipLaunchKernelGGL(ln_k, dim3(MROWS), dim3(256), 0, stream,
                           t, ln1_s + i * DDIM, ln1_b + i * DDIM, (float*)nullptr, h_bf, (long)DDIM);
        hipLaunchKernelGGL(gemm_bf16_k, dim3((3 * DDIM) / 128, MPAD / 128), dim3(256), 0, stream,
                           h_bf, wq_bf, (const float*)nullptr, (const float*)nullptr,
                           qkvbuf, (ushortT*)nullptr, 3 * DDIM, DDIM, 16);
        hipLaunchKernelGGL(qkvrope_k, dim3(1024), dim3(256), 0, stream,
                           qkvbuf, sin_t, cos_t, qb, kb, vb);
        hipLaunchKernelGGL(attn_k, dim3(96 * QT), dim3(256), 0, stream, qb, kb, vb, o_bf);
        hipLaunchKernelGGL(gemm_bf16_k, dim3(DDIM / 128, MPAD / 128), dim3(256), 0, stream,
                           o_bf, wp_bf, proj_b + i * DDIM, t, t, (ushortT*)nullptr,
                           DDIM, DDIM, 1 | 2 | 16);
        hipLaunchKernelGGL(ln_k, dim3(MROWS), dim3(256), 0, stream,
                           t, ln2_s + i * DDIM, ln2_b + i * DDIM, (float*)nullptr, h_bf, (long)DDIM);
        hipLaunchKernelGGL(gemm_bf16_k, dim3(NHID / 128, MPAD / 128), dim3(256), 0, stream,
                           h_bf, w1_bf, mlp_b1 + i * NHID, (const float*)nullptr,
                           (float*)nullptr, mlp_bf, NHID, DDIM, 1 | 4 | 32);
        hipLaunchKernelGGL(gemm_bf16_k, dim3(DDIM / 128, MPAD / 128), dim3(256), 0, stream,
                           mlp_bf, w2_bf, mlp_b2 + i * DDIM, t, t, (ushortT*)nullptr,
                           DDIM, NHID, 1 | 2 | 16);
    }
    hipLaunchKernelGGL(ln_k, dim3(NB), dim3(256), 0, stream,
                       t, norm_s, norm_b, (float*)d_out, (ushortT*)nullptr, (long)NL * DDIM);
}

// Round 3
// 4021.961 us; speedup vs baseline: 11.1015x; 3.6723x over previous
//
#include <hip/hip_runtime.h>
#include <math.h>

#define NB 8
#define DDIM 768
#define NHEAD 12
#define NDEPTH 12
#define HDIM 64
#define GRIDW 24
#define NL0 576
#define NL 577
#define LPAD 640
#define NHID 3072
#define MROWS (NB*NL)     // 4616
#define MPAD 4736         // 37*128
#define EPSV 1e-5f
#define QTILES 10

typedef unsigned short ushortT;
typedef __attribute__((ext_vector_type(8))) short bf16x8;
typedef __attribute__((ext_vector_type(4))) float f32x4;

__device__ __forceinline__ ushortT f2b(float f) {
    union { float f; unsigned u; } x; x.f = f;
    unsigned r = x.u + 0x7fffu + ((x.u >> 16) & 1u);
    return (ushortT)(r >> 16);
}

__device__ __forceinline__ void load_lds16(const void* g, void* l) {
    __builtin_amdgcn_global_load_lds((const __attribute__((address_space(1))) void*)g,
                                     (__attribute__((address_space(3))) void*)l, 16, 0, 0);
}

// ---------------- fp32 -> bf16 convert ----------------
__global__ void f2b_k(const float* __restrict__ in, ushortT* __restrict__ out, long n) {
    for (long i = ((long)blockIdx.x * 256 + threadIdx.x) * 4; i < n; i += (long)gridDim.x * 1024) {
        float4 v = *(const float4*)(in + i);
        ushort4 o; o.x = f2b(v.x); o.y = f2b(v.y); o.z = f2b(v.z); o.w = f2b(v.w);
        *(ushort4*)(out + i) = o;
    }
}

// ---------------- im2col -> bf16 patches[4608, 768] ----------------
__global__ void im2col_k(const float* __restrict__ x, ushortT* __restrict__ p) {
    for (long idx = (long)blockIdx.x * 256 + threadIdx.x; idx < (long)4608 * 768; idx += (long)gridDim.x * 256) {
        int row = (int)(idx / 768), col = (int)(idx - (long)row * 768);
        int b = row / NL0, pi = row - b * NL0;
        int gy = pi / GRIDW, gx = pi - gy * GRIDW;
        int c = col >> 8, r = col & 255;
        int py = r >> 4, px = r & 15;
        p[idx] = f2b(x[(((long)(b * 3 + c) * 384) + gy * 16 + py) * 384 + gx * 16 + px]);
    }
}

__global__ void cls_k(const float* __restrict__ cls, float* __restrict__ t) {
    t[(long)blockIdx.x * NL * DDIM + threadIdx.x] = cls[threadIdx.x];
}

__global__ void rope_k(float* __restrict__ sin_t, float* __restrict__ cos_t) {
    int pos = blockIdx.x, d = threadIdx.x;
    int gy = pos / GRIDW, gx = pos - gy * GRIDW;
    int j = d >> 1;
    float ang;
    if (j < 16) ang = (float)gy * powf(10000.f, -(float)j / 16.f);
    else        ang = (float)gx * powf(10000.f, -(float)(j - 16) / 16.f);
    sin_t[pos * 64 + d] = sinf(ang);
    cos_t[pos * 64 + d] = cosf(ang);
}

// ---------------- LayerNorm, one block per row; bf16 or fp32 out ----------------
__global__ __launch_bounds__(256) void ln_k(const float* __restrict__ in,
                                            const float* __restrict__ sc,
                                            const float* __restrict__ bi,
                                            float* __restrict__ outf,
                                            ushortT* __restrict__ outb,
                                            long in_rstride) {
    int row = blockIdx.x;
    const float* ip = in + (long)row * in_rstride;
    float x[3];
    float s = 0.f, s2 = 0.f;
    #pragma unroll
    for (int i = 0; i < 3; ++i) {
        x[i] = ip[threadIdx.x + i * 256];
        s += x[i]; s2 += x[i] * x[i];
    }
    __shared__ float red0[256], red1[256];
    red0[threadIdx.x] = s; red1[threadIdx.x] = s2;
    __syncthreads();
    for (int off = 128; off; off >>= 1) {
        if (threadIdx.x < off) {
            red0[threadIdx.x] += red0[threadIdx.x + off];
            red1[threadIdx.x] += red1[threadIdx.x + off];
        }
        __syncthreads();
    }
    float mean = red0[0] * (1.f / 768.f);
    float var  = red1[0] * (1.f / 768.f) - mean * mean;
    float inv = rsqrtf(var + EPSV);
    #pragma unroll
    for (int i = 0; i < 3; ++i) {
        int c = threadIdx.x + i * 256;
        float val = (x[i] - mean) * inv * sc[c] + bi[c];
        if (outb) outb[(long)row * 768 + c] = f2b(val);
        else      outf[(long)row * 768 + c] = val;
    }
}

// ---------------- bf16 MFMA GEMM: C[M,N] = A[M,K] @ W[N,K]^T ----------------
// flags: 1=bias 2=resid(f32) 4=gelu 8=remap(576->577) 16=store f32 32=store bf16
//        64=qkv mode (RoPE + scale + scatter to q/k/v^T)
__global__ __launch_bounds__(256) void gemm_bf16_k(const ushortT* __restrict__ A,
                                                   const ushortT* __restrict__ W,
                                                   const float* __restrict__ bias,
                                                   const float* __restrict__ resid,
                                                   float* __restrict__ Cf,
                                                   ushortT* __restrict__ Cb,
                                                   const float* __restrict__ sinT,
                                                   const float* __restrict__ cosT,
                                                   ushortT* __restrict__ qo,
                                                   ushortT* __restrict__ ko,
                                                   ushortT* __restrict__ vo,
                                                   int N, int K, int flags) {
    __shared__ ushortT As[128 * 64];
    __shared__ ushortT Bs[128 * 64];
    int tid = threadIdx.x;
    int lane = tid & 63, wid = tid >> 6;
    int wm = wid >> 1, wn = wid & 1;
    int lr = lane & 15, lk = lane >> 4;
    int m0 = blockIdx.y * 128, n0 = blockIdx.x * 128;
    f32x4 acc[4][4] = {};
    for (int kt = 0; kt < K; kt += 64) {
        #pragma unroll
        for (int i = 0; i < 4; ++i) {
            int ch = i * 256 + tid;
            int r = ch >> 3, c = (ch & 7) * 8;
            load_lds16(A + (size_t)(m0 + r) * K + kt + c, As + ch * 8);
        }
        #pragma unroll
        for (int i = 0; i < 4; ++i) {
            int ch = i * 256 + tid;
            int r = ch >> 3, c = (ch & 7) * 8;
            load_lds16(W + (size_t)(n0 + r) * K + kt + c, Bs + ch * 8);
        }
        __syncthreads();
        #pragma unroll
        for (int ks = 0; ks < 2; ++ks) {
            bf16x8 aF[4], bF[4];
            #pragma unroll
            for (int mi = 0; mi < 4; ++mi)
                aF[mi] = *(const bf16x8*)&As[(wm * 64 + mi * 16 + lr) * 64 + ks * 32 + lk * 8];
            #pragma unroll
            for (int ni = 0; ni < 4; ++ni)
                bF[ni] = *(const bf16x8*)&Bs[(wn * 64 + ni * 16 + lr) * 64 + ks * 32 + lk * 8];
            #pragma unroll
            for (int mi = 0; mi < 4; ++mi)
                #pragma unroll
                for (int ni = 0; ni < 4; ++ni)
                    acc[mi][ni] = __builtin_amdgcn_mfma_f32_16x16x32_bf16(aF[mi], bF[ni], acc[mi][ni], 0, 0, 0);
        }
        __syncthreads();
    }
    if (flags & 64) {
        // qkv mode: RoPE(q,k) + 0.125 scale on q + scatter; v stored transposed
        #pragma unroll
        for (int mi = 0; mi < 4; ++mi) {
            #pragma unroll
            for (int r = 0; r < 4; ++r) {
                int row = m0 + wm * 64 + mi * 16 + (lane >> 4) * 4 + r;
                if (row >= MROWS) continue;
                int b = row / NL, l = row - b * NL;
                #pragma unroll
                for (int ni = 0; ni < 4; ++ni) {
                    int c = n0 + wn * 64 + ni * 16 + lr;
                    float val = acc[mi][ni][r];
                    int sel = c / DDIM;
                    int cc = c - sel * DDIM;
                    int h = cc >> 6, d = cc & 63;
                    if (sel < 2 && l > 0) {
                        int pos = l - 1;
                        float cs = cosT[pos * 64 + d], sn = sinT[pos * 64 + d];
                        float partner = acc[mi][ni ^ 2][r];
                        float rh = (d < 32) ? -partner : partner;
                        val = val * cs + rh * sn;
                    }
                    int bh = b * NHEAD + h;
                    if (sel == 0)      qo[((long)bh * LPAD + l) * HDIM + d] = f2b(val * 0.125f);
                    else if (sel == 1) ko[((long)bh * LPAD + l) * HDIM + d] = f2b(val);
                    else               vo[((long)bh * HDIM + d) * LPAD + l] = f2b(val);
                }
            }
        }
        return;
    }
    #pragma unroll
    for (int mi = 0; mi < 4; ++mi) {
        int rbase = m0 + wm * 64 + mi * 16 + (lane >> 4) * 4;
        #pragma unroll
        for (int ni = 0; ni < 4; ++ni) {
            int c = n0 + wn * 64 + ni * 16 + lr;
            float bv = (flags & 1) ? bias[c] : 0.f;
            #pragma unroll
            for (int r = 0; r < 4; ++r) {
                int row = rbase + r;
                float val = acc[mi][ni][r] + bv;
                if (flags & 4) val = 0.5f * val * (1.f + erff(val * 0.70710678118654752f));
                long orow = row;
                if (flags & 8) orow = (long)(row / NL0) * NL + 1 + (row % NL0);
                if (flags & 2) val += resid[orow * (long)N + c];
                if (flags & 16) Cf[orow * (long)N + c] = val;
                if (flags & 32) Cb[orow * (long)N + c] = f2b(val);
            }
        }
    }
}

// ---------------- MFMA flash attention ----------------
// grid = 96 heads x 10 q-tiles; block = 256 (4 waves, 16 q-rows each)
__global__ __launch_bounds__(256) void fattn_k(const ushortT* __restrict__ q,
                                               const ushortT* __restrict__ k,
                                               const ushortT* __restrict__ vt,
                                               ushortT* __restrict__ o) {
    __shared__ ushortT Qs[4096], Ks[4096], Vs[4096], Ps[4096];
    int tid = threadIdx.x;
    int wave = tid >> 6, lane = tid & 63;
    int lr = lane & 15, lk = lane >> 4, g = lk;
    int bh = blockIdx.x / QTILES, qt = blockIdx.x % QTILES;
    int q0 = qt * 64;
    int b = bh / NHEAD, h = bh - b * NHEAD;
    int l8 = lane >> 3, c16 = lane & 7;
    int colsw = (c16 * 16) ^ ((l8 & 7) << 4);   // pre-swizzled byte offset within 128B row

    // stage Q tile (64 x 64 bf16), swizzled
    {
        const ushortT* src = q + ((long)bh * LPAD + q0) * HDIM;
        #pragma unroll
        for (int j = 0; j < 2; ++j) {
            int row = wave * 16 + j * 8 + l8;
            load_lds16(src + (long)row * HDIM + (colsw >> 1), Qs + wave * 1024 + j * 512);
        }
    }
    __syncthreads();
    bf16x8 qF[2];
    #pragma unroll
    for (int ks = 0; ks < 2; ++ks) {
        int row = wave * 16 + lr;
        qF[ks] = *(const bf16x8*)((const char*)Qs + row * 128 + ((ks * 64 + lk * 16) ^ ((lr & 7) << 4)));
    }
    f32x4 oa[4] = {};
    float m_r[4], l_r[4];
    #pragma unroll
    for (int r = 0; r < 4; ++r) { m_r[r] = -3e38f; l_r[r] = 0.f; }

    for (int t0 = 0; t0 < QTILES; ++t0) {
        int k0 = t0 * 64;
        __syncthreads();   // previous tile's readers done before restage
        {
            const ushortT* srck = k + ((long)bh * LPAD + k0) * HDIM;
            const ushortT* srcv = vt + (long)bh * HDIM * LPAD + k0;
            #pragma unroll
            for (int j = 0; j < 2; ++j) {
                int row = wave * 16 + j * 8 + l8;
                load_lds16(srck + (long)row * HDIM + (colsw >> 1), Ks + wave * 1024 + j * 512);
                load_lds16(srcv + (long)row * LPAD + (colsw >> 1), Vs + wave * 1024 + j * 512);
            }
        }
        __syncthreads();   // drains vmcnt before barrier
        f32x4 s[4] = {};
        #pragma unroll
        for (int ks = 0; ks < 2; ++ks) {
            #pragma unroll
            for (int kt = 0; kt < 4; ++kt) {
                int row = kt * 16 + lr;
                bf16x8 kF = *(const bf16x8*)((const char*)Ks + row * 128 + ((ks * 64 + lk * 16) ^ ((lr & 7) << 4)));
                s[kt] = __builtin_amdgcn_mfma_f32_16x16x32_bf16(qF[ks], kF, s[kt], 0, 0, 0);
            }
        }
        if (k0 + 63 > 576) {
            #pragma unroll
            for (int kt = 0; kt < 4; ++kt)
                if (k0 + kt * 16 + lr > 576) {
                    #pragma unroll
                    for (int r = 0; r < 4; ++r) s[kt][r] = -3e38f;
                }
        }
        float mx[4], al[4], rs[4];
        #pragma unroll
        for (int r = 0; r < 4; ++r)
            mx[r] = fmaxf(fmaxf(s[0][r], s[1][r]), fmaxf(s[2][r], s[3][r]));
        #pragma unroll
        for (int off = 1; off < 16; off <<= 1) {
            #pragma unroll
            for (int r = 0; r < 4; ++r) mx[r] = fmaxf(mx[r], __shfl_xor(mx[r], off));
        }
        #pragma unroll
        for (int r = 0; r < 4; ++r) {
            float mn = fmaxf(m_r[r], mx[r]);
            al[r] = __expf(m_r[r] - mn);
            m_r[r] = mn;
            rs[r] = 0.f;
        }
        #pragma unroll
        for (int kt = 0; kt < 4; ++kt) {
            #pragma unroll
            for (int r = 0; r < 4; ++r) {
                float p = __expf(s[kt][r] - m_r[r]);
                rs[r] += p;
                int rowp = g * 4 + r;
                *(ushortT*)((char*)Ps + wave * 2048 + rowp * 128 +
                            ((kt * 32 + lr * 2) ^ ((rowp & 7) << 4))) = f2b(p);
            }
        }
        #pragma unroll
        for (int off = 1; off < 16; off <<= 1) {
            #pragma unroll
            for (int r = 0; r < 4; ++r) rs[r] += __shfl_xor(rs[r], off);
        }
        #pragma unroll
        for (int r = 0; r < 4; ++r) l_r[r] = l_r[r] * al[r] + rs[r];
        #pragma unroll
        for (int dt = 0; dt < 4; ++dt) {
            #pragma unroll
            for (int r = 0; r < 4; ++r) oa[dt][r] *= al[r];
        }
        __syncthreads();   // own P writes visible (lgkm drained by barrier)
        #pragma unroll
        for (int ks = 0; ks < 2; ++ks) {
            bf16x8 pA = *(const bf16x8*)((const char*)Ps + wave * 2048 + lr * 128 +
                                         ((ks * 64 + lk * 16) ^ ((lr & 7) << 4)));
            #pragma unroll
            for (int dt = 0; dt < 4; ++dt) {
                bf16x8 vF = *(const bf16x8*)((const char*)Vs + (dt * 16 + lr) * 128 +
                                             ((ks * 64 + lk * 16) ^ ((lr & 7) << 4)));
                oa[dt] = __builtin_amdgcn_mfma_f32_16x16x32_bf16(pA, vF, oa[dt], 0, 0, 0);
            }
        }
    }
    #pragma unroll
    for (int r = 0; r < 4; ++r) {
        int l = q0 + wave * 16 + g * 4 + r;
        if (l > 576) continue;
        float inv = 1.f / l_r[r];
        #pragma unroll
        for (int dt = 0; dt < 4; ++dt)
            o[((long)(b * NL + l)) * DDIM + h * HDIM + dt * 16 + lr] = f2b(oa[dt][r] * inv);
    }
}

extern "C" void kernel_launch(void* const* d_in, const int* in_sizes, int n_in,
                              void* d_out, int out_size, void* d_ws, size_t ws_size,
                              hipStream_t stream) {
    const float* x       = (const float*)d_in[0];
    const float* patch_w = (const float*)d_in[1];
    const float* patch_b = (const float*)d_in[2];
    const float* cls     = (const float*)d_in[3];
    const float* ln1_s   = (const float*)d_in[4];
    const float* ln1_b   = (const float*)d_in[5];
    const float* qkv_w   = (const float*)d_in[6];
    const float* proj_w  = (const float*)d_in[7];
    const float* proj_b  = (const float*)d_in[8];
    const float* ln2_s   = (const float*)d_in[9];
    const float* ln2_b   = (const float*)d_in[10];
    const float* mlp_w1  = (const float*)d_in[11];
    const float* mlp_b1  = (const float*)d_in[12];
    const float* mlp_w2  = (const float*)d_in[13];
    const float* mlp_b2  = (const float*)d_in[14];
    const float* norm_s  = (const float*)d_in[15];
    const float* norm_b  = (const float*)d_in[16];

    char* w = (char*)d_ws;
    float* t      = (float*)w;  w += (size_t)MPAD * DDIM * 4;
    float* sin_t  = (float*)w;  w += (size_t)NL0 * HDIM * 4;
    float* cos_t  = (float*)w;  w += (size_t)NL0 * HDIM * 4;
    ushortT* h_bf   = (ushortT*)w; w += (size_t)MPAD * DDIM * 2;
    ushortT* o_bf   = (ushortT*)w; w += (size_t)MPAD * DDIM * 2;
    ushortT* mlp_bf = (ushortT*)w; w += (size_t)MPAD * NHID * 2;
    ushortT* patches = mlp_bf;    // alias: disjoint lifetime (pre-loop only)
    ushortT* q_bf   = (ushortT*)w; w += (size_t)96 * LPAD * HDIM * 2;
    ushortT* k_bf   = (ushortT*)w; w += (size_t)96 * LPAD * HDIM * 2;
    ushortT* v_t    = (ushortT*)w; w += (size_t)96 * HDIM * LPAD * 2;
    ushortT* pw_bf  = (ushortT*)w; w += (size_t)DDIM * 768 * 2;
    ushortT* wq_bf  = (ushortT*)w; w += (size_t)3 * DDIM * DDIM * 2;
    ushortT* wp_bf  = (ushortT*)w; w += (size_t)DDIM * DDIM * 2;
    ushortT* w1_bf  = (ushortT*)w; w += (size_t)NHID * DDIM * 2;
    ushortT* w2_bf  = (ushortT*)w; w += (size_t)DDIM * NHID * 2;

    hipLaunchKernelGGL(rope_k, dim3(NL0), dim3(64), 0, stream, sin_t, cos_t);
    hipLaunchKernelGGL(im2col_k, dim3(2048), dim3(256), 0, stream, x, patches);
    hipLaunchKernelGGL(f2b_k, dim3(512), dim3(256), 0, stream, patch_w, pw_bf, (long)DDIM * 768);
    hipLaunchKernelGGL(cls_k, dim3(NB), dim3(DDIM), 0, stream, cls, t);
    hipLaunchKernelGGL(gemm_bf16_k, dim3(DDIM / 128, 4608 / 128), dim3(256), 0, stream,
                       patches, pw_bf, patch_b, (const float*)nullptr, t, (ushortT*)nullptr,
                       (const float*)nullptr, (const float*)nullptr,
                       (ushortT*)nullptr, (ushortT*)nullptr, (ushortT*)nullptr,
                       DDIM, 768, 1 | 8 | 16);

    for (int i = 0; i < NDEPTH; ++i) {
        hipLaunchKernelGGL(f2b_k, dim3(1024), dim3(256), 0, stream,
                           qkv_w + (size_t)i * 3 * DDIM * DDIM, wq_bf, (long)3 * DDIM * DDIM);
        hipLaunchKernelGGL(f2b_k, dim3(512), dim3(256), 0, stream,
                           proj_w + (size_t)i * DDIM * DDIM, wp_bf, (long)DDIM * DDIM);
        hipLaunchKernelGGL(f2b_k, dim3(1024), dim3(256), 0, stream,
                           mlp_w1 + (size_t)i * NHID * DDIM, w1_bf, (long)NHID * DDIM);
        hipLaunchKernelGGL(f2b_k, dim3(1024), dim3(256), 0, stream,
                           mlp_w2 + (size_t)i * DDIM * NHID, w2_bf, (long)DDIM * NHID);

        hipLaunchKernelGGL(ln_k, dim3(MROWS), dim3(256), 0, stream,
                           t, ln1_s + i * DDIM, ln1_b + i * DDIM, (float*)nullptr, h_bf, (long)DDIM);
        // QKV GEMM with fused RoPE + scatter
        hipLaunchKernelGGL(gemm_bf16_k, dim3((3 * DDIM) / 128, MPAD / 128), dim3(256), 0, stream,
                           h_bf, wq_bf, (const float*)nullptr, (const float*)nullptr,
                           (float*)nullptr, (ushortT*)nullptr, sin_t, cos_t,
                           q_bf, k_bf, v_t, 3 * DDIM, DDIM, 64);
        hipLaunchKernelGGL(fattn_k, dim3(96 * QTILES), dim3(256), 0, stream,
                           q_bf, k_bf, v_t, o_bf);
        hipLaunchKernelGGL(gemm_bf16_k, dim3(DDIM / 128, MPAD / 128), dim3(256), 0, stream,
                           o_bf, wp_bf, proj_b + i * DDIM, t, t, (ushortT*)nullptr,
                           (const float*)nullptr, (const float*)nullptr,
                           (ushortT*)nullptr, (ushortT*)nullptr, (ushortT*)nullptr,
                           DDIM, DDIM, 1 | 2 | 16);
        hipLaunchKernelGGL(ln_k, dim3(MROWS), dim3(256), 0, stream,
                           t, ln2_s + i * DDIM, ln2_b + i * DDIM, (float*)nullptr, h_bf, (long)DDIM);
        hipLaunchKernelGGL(gemm_bf16_k, dim3(NHID / 128, MPAD / 128), dim3(256), 0, stream,
                           h_bf, w1_bf, mlp_b1 + i * NHID, (const float*)nullptr,
                           (float*)nullptr, mlp_bf, (const float*)nullptr, (const float*)nullptr,
                           (ushortT*)nullptr, (ushortT*)nullptr, (ushortT*)nullptr,
                           NHID, DDIM, 1 | 4 | 32);
        hipLaunchKernelGGL(gemm_bf16_k, dim3(DDIM / 128, MPAD / 128), dim3(256), 0, stream,
                           mlp_bf, w2_bf, mlp_b2 + i * DDIM, t, t, (ushortT*)nullptr,
                           (const float*)nullptr, (const float*)nullptr,
                           (ushortT*)nullptr, (ushortT*)nullptr, (ushortT*)nullptr,
                           DDIM, NHID, 1 | 2 | 16);
    }
    hipLaunchKernelGGL(ln_k, dim3(NB), dim3(256), 0, stream,
                       t, norm_s, norm_b, (float*)d_out, (ushortT*)nullptr, (long)NL * DDIM);
}

// Round 4
// 3729.642 us; speedup vs baseline: 11.9716x; 1.0784x over previous
//
#include <hip/hip_runtime.h>
#include <math.h>

#define NB 8
#define DDIM 768
#define NHEAD 12
#define NDEPTH 12
#define HDIM 64
#define GRIDW 24
#define NL0 576
#define NL 577
#define LPAD 640
#define NHID 3072
#define MROWS (NB*NL)     // 4616
#define MPAD 4736         // 37*128
#define EPSV 1e-5f
#define QTILES 10

typedef unsigned short ushortT;
typedef __attribute__((ext_vector_type(8))) short bf16x8;
typedef __attribute__((ext_vector_type(4))) float f32x4;

__device__ __forceinline__ ushortT f2b(float f) {
    union { float f; unsigned u; } x; x.f = f;
    unsigned r = x.u + 0x7fffu + ((x.u >> 16) & 1u);
    return (ushortT)(r >> 16);
}

__device__ __forceinline__ void load_lds16(const void* g, void* l) {
    __builtin_amdgcn_global_load_lds((const __attribute__((address_space(1))) void*)g,
                                     (__attribute__((address_space(3))) void*)l, 16, 0, 0);
}

// ---------------- fp32 -> bf16 convert (single array) ----------------
__global__ void f2b_k(const float* __restrict__ in, ushortT* __restrict__ out, long n) {
    for (long i = ((long)blockIdx.x * 256 + threadIdx.x) * 4; i < n; i += (long)gridDim.x * 1024) {
        float4 v = *(const float4*)(in + i);
        ushort4 o; o.x = f2b(v.x); o.y = f2b(v.y); o.z = f2b(v.z); o.w = f2b(v.w);
        *(ushort4*)(out + i) = o;
    }
}

// ---------------- per-layer 4-weight convert, one launch ----------------
__global__ void wconv4_k(const float* __restrict__ a, ushortT* __restrict__ ao, long na,
                         const float* __restrict__ b, ushortT* __restrict__ bo, long nb,
                         const float* __restrict__ c, ushortT* __restrict__ co, long nc,
                         const float* __restrict__ d, ushortT* __restrict__ dd, long nd) {
    long stride = (long)gridDim.x * 1024;
    long i0 = ((long)blockIdx.x * 256 + threadIdx.x) * 4;
    for (long i = i0; i < na; i += stride) {
        float4 v = *(const float4*)(a + i);
        ushort4 o; o.x = f2b(v.x); o.y = f2b(v.y); o.z = f2b(v.z); o.w = f2b(v.w);
        *(ushort4*)(ao + i) = o;
    }
    for (long i = i0; i < nb; i += stride) {
        float4 v = *(const float4*)(b + i);
        ushort4 o; o.x = f2b(v.x); o.y = f2b(v.y); o.z = f2b(v.z); o.w = f2b(v.w);
        *(ushort4*)(bo + i) = o;
    }
    for (long i = i0; i < nc; i += stride) {
        float4 v = *(const float4*)(c + i);
        ushort4 o; o.x = f2b(v.x); o.y = f2b(v.y); o.z = f2b(v.z); o.w = f2b(v.w);
        *(ushort4*)(co + i) = o;
    }
    for (long i = i0; i < nd; i += stride) {
        float4 v = *(const float4*)(d + i);
        ushort4 o; o.x = f2b(v.x); o.y = f2b(v.y); o.z = f2b(v.z); o.w = f2b(v.w);
        *(ushort4*)(dd + i) = o;
    }
}

// ---------------- im2col -> bf16 patches[4608, 768] ----------------
__global__ void im2col_k(const float* __restrict__ x, ushortT* __restrict__ p) {
    for (long idx = (long)blockIdx.x * 256 + threadIdx.x; idx < (long)4608 * 768; idx += (long)gridDim.x * 256) {
        int row = (int)(idx / 768), col = (int)(idx - (long)row * 768);
        int b = row / NL0, pi = row - b * NL0;
        int gy = pi / GRIDW, gx = pi - gy * GRIDW;
        int c = col >> 8, r = col & 255;
        int py = r >> 4, px = r & 15;
        p[idx] = f2b(x[(((long)(b * 3 + c) * 384) + gy * 16 + py) * 384 + gx * 16 + px]);
    }
}

__global__ void cls_k(const float* __restrict__ cls, float* __restrict__ t) {
    t[(long)blockIdx.x * NL * DDIM + threadIdx.x] = cls[threadIdx.x];
}

__global__ void rope_k(float* __restrict__ sin_t, float* __restrict__ cos_t) {
    int pos = blockIdx.x, d = threadIdx.x;
    int gy = pos / GRIDW, gx = pos - gy * GRIDW;
    int j = d >> 1;
    float ang;
    if (j < 16) ang = (float)gy * powf(10000.f, -(float)j / 16.f);
    else        ang = (float)gx * powf(10000.f, -(float)(j - 16) / 16.f);
    sin_t[pos * 64 + d] = sinf(ang);
    cos_t[pos * 64 + d] = cosf(ang);
}

// ---------------- LayerNorm, one block per row; bf16 or fp32 out ----------------
__global__ __launch_bounds__(256) void ln_k(const float* __restrict__ in,
                                            const float* __restrict__ sc,
                                            const float* __restrict__ bi,
                                            float* __restrict__ outf,
                                            ushortT* __restrict__ outb,
                                            long in_rstride) {
    int row = blockIdx.x;
    const float* ip = in + (long)row * in_rstride;
    float x[3];
    float s = 0.f, s2 = 0.f;
    #pragma unroll
    for (int i = 0; i < 3; ++i) {
        x[i] = ip[threadIdx.x + i * 256];
        s += x[i]; s2 += x[i] * x[i];
    }
    __shared__ float red0[256], red1[256];
    red0[threadIdx.x] = s; red1[threadIdx.x] = s2;
    __syncthreads();
    for (int off = 128; off; off >>= 1) {
        if (threadIdx.x < off) {
            red0[threadIdx.x] += red0[threadIdx.x + off];
            red1[threadIdx.x] += red1[threadIdx.x + off];
        }
        __syncthreads();
    }
    float mean = red0[0] * (1.f / 768.f);
    float var  = red1[0] * (1.f / 768.f) - mean * mean;
    float inv = rsqrtf(var + EPSV);
    #pragma unroll
    for (int i = 0; i < 3; ++i) {
        int c = threadIdx.x + i * 256;
        float val = (x[i] - mean) * inv * sc[c] + bi[c];
        if (outb) outb[(long)row * 768 + c] = f2b(val);
        else      outf[(long)row * 768 + c] = val;
    }
}

// ---------------- bf16 MFMA GEMM: C[M,N] = A[M,K] @ W[N,K]^T ----------------
// flags: 1=bias 2=resid(f32) 4=gelu 8=remap(576->577) 16=store f32 32=store bf16
//        64=qkv mode (RoPE + scale + scatter to q/k/v^T)
// LDS tiles XOR-swizzled (T2): linear global_load_lds dest + inverse-swizzled
// global source; fragment ds_read_b128 applies the same involution.
// blockIdx remapped so each XCD owns a contiguous M-stripe (T1, m204 bijective).
__global__ __launch_bounds__(256) void gemm_bf16_k(const ushortT* __restrict__ A,
                                                   const ushortT* __restrict__ W,
                                                   const float* __restrict__ bias,
                                                   const float* __restrict__ resid,
                                                   float* __restrict__ Cf,
                                                   ushortT* __restrict__ Cb,
                                                   const float* __restrict__ sinT,
                                                   const float* __restrict__ cosT,
                                                   ushortT* __restrict__ qo,
                                                   ushortT* __restrict__ ko,
                                                   ushortT* __restrict__ vo,
                                                   int N, int K, int flags) {
    __shared__ ushortT As[128 * 64];
    __shared__ ushortT Bs[128 * 64];
    int tid = threadIdx.x;
    int lane = tid & 63, wid = tid >> 6;
    int wm = wid >> 1, wn = wid & 1;
    int lr = lane & 15, lk = lane >> 4;
    // T1: bijective XCD chunking
    int nwg = gridDim.x * gridDim.y;
    int flat = blockIdx.y * gridDim.x + blockIdx.x;
    int qq = nwg >> 3, rr = nwg & 7;
    int xcd = flat & 7, idx = flat >> 3;
    int wg = (xcd < rr ? xcd * (qq + 1) : rr * (qq + 1) + (xcd - rr) * qq) + idx;
    int bx = wg % gridDim.x, by = wg / gridDim.x;
    int m0 = by * 128, n0 = bx * 128;
    f32x4 acc[4][4] = {};
    for (int kt = 0; kt < K; kt += 64) {
        #pragma unroll
        for (int i = 0; i < 4; ++i) {
            int ch = i * 256 + tid;
            int r = ch >> 3, cb = (ch & 7) * 16;          // col byte
            int cbs = cb ^ ((r & 7) << 4);                // inverse-swizzled source col
            load_lds16(A + (size_t)(m0 + r) * K + kt + (cbs >> 1), As + ch * 8);
        }
        #pragma unroll
        for (int i = 0; i < 4; ++i) {
            int ch = i * 256 + tid;
            int r = ch >> 3, cb = (ch & 7) * 16;
            int cbs = cb ^ ((r & 7) << 4);
            load_lds16(W + (size_t)(n0 + r) * K + kt + (cbs >> 1), Bs + ch * 8);
        }
        __syncthreads();
        #pragma unroll
        for (int ks = 0; ks < 2; ++ks) {
            bf16x8 aF[4], bF[4];
            #pragma unroll
            for (int mi = 0; mi < 4; ++mi) {
                int row = wm * 64 + mi * 16 + lr;
                aF[mi] = *(const bf16x8*)((const char*)As + row * 128 +
                                          ((ks * 64 + lk * 16) ^ ((row & 7) << 4)));
            }
            #pragma unroll
            for (int ni = 0; ni < 4; ++ni) {
                int row = wn * 64 + ni * 16 + lr;
                bF[ni] = *(const bf16x8*)((const char*)Bs + row * 128 +
                                          ((ks * 64 + lk * 16) ^ ((row & 7) << 4)));
            }
            #pragma unroll
            for (int mi = 0; mi < 4; ++mi)
                #pragma unroll
                for (int ni = 0; ni < 4; ++ni)
                    acc[mi][ni] = __builtin_amdgcn_mfma_f32_16x16x32_bf16(aF[mi], bF[ni], acc[mi][ni], 0, 0, 0);
        }
        __syncthreads();
    }
    if (flags & 64) {
        #pragma unroll
        for (int mi = 0; mi < 4; ++mi) {
            #pragma unroll
            for (int r = 0; r < 4; ++r) {
                int row = m0 + wm * 64 + mi * 16 + (lane >> 4) * 4 + r;
                if (row >= MROWS) continue;
                int b = row / NL, l = row - b * NL;
                #pragma unroll
                for (int ni = 0; ni < 4; ++ni) {
                    int c = n0 + wn * 64 + ni * 16 + lr;
                    float val = acc[mi][ni][r];
                    int sel = c / DDIM;
                    int cc = c - sel * DDIM;
                    int h = cc >> 6, d = cc & 63;
                    if (sel < 2 && l > 0) {
                        int pos = l - 1;
                        float cs = cosT[pos * 64 + d], sn = sinT[pos * 64 + d];
                        float partner = acc[mi][ni ^ 2][r];
                        float rh = (d < 32) ? -partner : partner;
                        val = val * cs + rh * sn;
                    }
                    int bh = b * NHEAD + h;
                    if (sel == 0)      qo[((long)bh * LPAD + l) * HDIM + d] = f2b(val * 0.125f);
                    else if (sel == 1) ko[((long)bh * LPAD + l) * HDIM + d] = f2b(val);
                    else               vo[((long)bh * HDIM + d) * LPAD + l] = f2b(val);
                }
            }
        }
        return;
    }
    #pragma unroll
    for (int mi = 0; mi < 4; ++mi) {
        int rbase = m0 + wm * 64 + mi * 16 + (lane >> 4) * 4;
        #pragma unroll
        for (int ni = 0; ni < 4; ++ni) {
            int c = n0 + wn * 64 + ni * 16 + lr;
            float bv = (flags & 1) ? bias[c] : 0.f;
            #pragma unroll
            for (int r = 0; r < 4; ++r) {
                int row = rbase + r;
                float val = acc[mi][ni][r] + bv;
                if (flags & 4) val = 0.5f * val * (1.f + erff(val * 0.70710678118654752f));
                long orow = row;
                if (flags & 8) orow = (long)(row / NL0) * NL + 1 + (row % NL0);
                if (flags & 2) val += resid[orow * (long)N + c];
                if (flags & 16) Cf[orow * (long)N + c] = val;
                if (flags & 32) Cb[orow * (long)N + c] = f2b(val);
            }
        }
    }
}

// ---------------- MFMA flash attention ----------------
__global__ __launch_bounds__(256) void fattn_k(const ushortT* __restrict__ q,
                                               const ushortT* __restrict__ k,
                                               const ushortT* __restrict__ vt,
                                               ushortT* __restrict__ o) {
    __shared__ ushortT Qs[4096], Ks[4096], Vs[4096], Ps[4096];
    int tid = threadIdx.x;
    int wave = tid >> 6, lane = tid & 63;
    int lr = lane & 15, lk = lane >> 4, g = lk;
    int bh = blockIdx.x / QTILES, qt = blockIdx.x % QTILES;
    int q0 = qt * 64;
    int b = bh / NHEAD, h = bh - b * NHEAD;
    int l8 = lane >> 3, c16 = lane & 7;
    int colsw = (c16 * 16) ^ ((l8 & 7) << 4);

    {
        const ushortT* src = q + ((long)bh * LPAD + q0) * HDIM;
        #pragma unroll
        for (int j = 0; j < 2; ++j) {
            int row = wave * 16 + j * 8 + l8;
            load_lds16(src + (long)row * HDIM + (colsw >> 1), Qs + wave * 1024 + j * 512);
        }
    }
    __syncthreads();
    bf16x8 qF[2];
    #pragma unroll
    for (int ks = 0; ks < 2; ++ks) {
        int row = wave * 16 + lr;
        qF[ks] = *(const bf16x8*)((const char*)Qs + row * 128 + ((ks * 64 + lk * 16) ^ ((lr & 7) << 4)));
    }
    f32x4 oa[4] = {};
    float m_r[4], l_r[4];
    #pragma unroll
    for (int r = 0; r < 4; ++r) { m_r[r] = -3e38f; l_r[r] = 0.f; }

    for (int t0 = 0; t0 < QTILES; ++t0) {
        int k0 = t0 * 64;
        __syncthreads();
        {
            const ushortT* srck = k + ((long)bh * LPAD + k0) * HDIM;
            const ushortT* srcv = vt + (long)bh * HDIM * LPAD + k0;
            #pragma unroll
            for (int j = 0; j < 2; ++j) {
                int row = wave * 16 + j * 8 + l8;
                load_lds16(srck + (long)row * HDIM + (colsw >> 1), Ks + wave * 1024 + j * 512);
                load_lds16(srcv + (long)row * LPAD + (colsw >> 1), Vs + wave * 1024 + j * 512);
            }
        }
        __syncthreads();
        f32x4 s[4] = {};
        #pragma unroll
        for (int ks = 0; ks < 2; ++ks) {
            #pragma unroll
            for (int kt = 0; kt < 4; ++kt) {
                int row = kt * 16 + lr;
                bf16x8 kF = *(const bf16x8*)((const char*)Ks + row * 128 + ((ks * 64 + lk * 16) ^ ((lr & 7) << 4)));
                s[kt] = __builtin_amdgcn_mfma_f32_16x16x32_bf16(qF[ks], kF, s[kt], 0, 0, 0);
            }
        }
        if (k0 + 63 > 576) {
            #pragma unroll
            for (int kt = 0; kt < 4; ++kt)
                if (k0 + kt * 16 + lr > 576) {
                    #pragma unroll
                    for (int r = 0; r < 4; ++r) s[kt][r] = -3e38f;
                }
        }
        float mx[4], al[4], rs[4];
        #pragma unroll
        for (int r = 0; r < 4; ++r)
            mx[r] = fmaxf(fmaxf(s[0][r], s[1][r]), fmaxf(s[2][r], s[3][r]));
        #pragma unroll
        for (int off = 1; off < 16; off <<= 1) {
            #pragma unroll
            for (int r = 0; r < 4; ++r) mx[r] = fmaxf(mx[r], __shfl_xor(mx[r], off));
        }
        #pragma unroll
        for (int r = 0; r < 4; ++r) {
            float mn = fmaxf(m_r[r], mx[r]);
            al[r] = __expf(m_r[r] - mn);
            m_r[r] = mn;
            rs[r] = 0.f;
        }
        #pragma unroll
        for (int kt = 0; kt < 4; ++kt) {
            #pragma unroll
            for (int r = 0; r < 4; ++r) {
                float p = __expf(s[kt][r] - m_r[r]);
                rs[r] += p;
                int rowp = g * 4 + r;
                *(ushortT*)((char*)Ps + wave * 2048 + rowp * 128 +
                            ((kt * 32 + lr * 2) ^ ((rowp & 7) << 4))) = f2b(p);
            }
        }
        #pragma unroll
        for (int off = 1; off < 16; off <<= 1) {
            #pragma unroll
            for (int r = 0; r < 4; ++r) rs[r] += __shfl_xor(rs[r], off);
        }
        #pragma unroll
        for (int r = 0; r < 4; ++r) l_r[r] = l_r[r] * al[r] + rs[r];
        #pragma unroll
        for (int dt = 0; dt < 4; ++dt) {
            #pragma unroll
            for (int r = 0; r < 4; ++r) oa[dt][r] *= al[r];
        }
        __syncthreads();
        #pragma unroll
        for (int ks = 0; ks < 2; ++ks) {
            bf16x8 pA = *(const bf16x8*)((const char*)Ps + wave * 2048 + lr * 128 +
                                         ((ks * 64 + lk * 16) ^ ((lr & 7) << 4)));
            #pragma unroll
            for (int dt = 0; dt < 4; ++dt) {
                bf16x8 vF = *(const bf16x8*)((const char*)Vs + (dt * 16 + lr) * 128 +
                                             ((ks * 64 + lk * 16) ^ ((lr & 7) << 4)));
                oa[dt] = __builtin_amdgcn_mfma_f32_16x16x32_bf16(pA, vF, oa[dt], 0, 0, 0);
            }
        }
    }
    #pragma unroll
    for (int r = 0; r < 4; ++r) {
        int l = q0 + wave * 16 + g * 4 + r;
        if (l > 576) continue;
        float inv = 1.f / l_r[r];
        #pragma unroll
        for (int dt = 0; dt < 4; ++dt)
            o[((long)(b * NL + l)) * DDIM + h * HDIM + dt * 16 + lr] = f2b(oa[dt][r] * inv);
    }
}

extern "C" void kernel_launch(void* const* d_in, const int* in_sizes, int n_in,
                              void* d_out, int out_size, void* d_ws, size_t ws_size,
                              hipStream_t stream) {
    const float* x       = (const float*)d_in[0];
    const float* patch_w = (const float*)d_in[1];
    const float* patch_b = (const float*)d_in[2];
    const float* cls     = (const float*)d_in[3];
    const float* ln1_s   = (const float*)d_in[4];
    const float* ln1_b   = (const float*)d_in[5];
    const float* qkv_w   = (const float*)d_in[6];
    const float* proj_w  = (const float*)d_in[7];
    const float* proj_b  = (const float*)d_in[8];
    const float* ln2_s   = (const float*)d_in[9];
    const float* ln2_b   = (const float*)d_in[10];
    const float* mlp_w1  = (const float*)d_in[11];
    const float* mlp_b1  = (const float*)d_in[12];
    const float* mlp_w2  = (const float*)d_in[13];
    const float* mlp_b2  = (const float*)d_in[14];
    const float* norm_s  = (const float*)d_in[15];
    const float* norm_b  = (const float*)d_in[16];

    char* w = (char*)d_ws;
    float* t      = (float*)w;  w += (size_t)MPAD * DDIM * 4;
    float* sin_t  = (float*)w;  w += (size_t)NL0 * HDIM * 4;
    float* cos_t  = (float*)w;  w += (size_t)NL0 * HDIM * 4;
    ushortT* h_bf   = (ushortT*)w; w += (size_t)MPAD * DDIM * 2;
    ushortT* o_bf   = (ushortT*)w; w += (size_t)MPAD * DDIM * 2;
    ushortT* mlp_bf = (ushortT*)w; w += (size_t)MPAD * NHID * 2;
    ushortT* patches = mlp_bf;    // alias: disjoint lifetime (pre-loop only)
    ushortT* q_bf   = (ushortT*)w; w += (size_t)96 * LPAD * HDIM * 2;
    ushortT* k_bf   = (ushortT*)w; w += (size_t)96 * LPAD * HDIM * 2;
    ushortT* v_t    = (ushortT*)w; w += (size_t)96 * HDIM * LPAD * 2;
    ushortT* pw_bf  = (ushortT*)w; w += (size_t)DDIM * 768 * 2;
    ushortT* wq_bf  = (ushortT*)w; w += (size_t)3 * DDIM * DDIM * 2;
    ushortT* wp_bf  = (ushortT*)w; w += (size_t)DDIM * DDIM * 2;
    ushortT* w1_bf  = (ushortT*)w; w += (size_t)NHID * DDIM * 2;
    ushortT* w2_bf  = (ushortT*)w; w += (size_t)DDIM * NHID * 2;

    hipLaunchKernelGGL(rope_k, dim3(NL0), dim3(64), 0, stream, sin_t, cos_t);
    hipLaunchKernelGGL(im2col_k, dim3(2048), dim3(256), 0, stream, x, patches);
    hipLaunchKernelGGL(f2b_k, dim3(512), dim3(256), 0, stream, patch_w, pw_bf, (long)DDIM * 768);
    hipLaunchKernelGGL(cls_k, dim3(NB), dim3(DDIM), 0, stream, cls, t);
    hipLaunchKernelGGL(gemm_bf16_k, dim3(DDIM / 128, 4608 / 128), dim3(256), 0, stream,
                       patches, pw_bf, patch_b, (const float*)nullptr, t, (ushortT*)nullptr,
                       (const float*)nullptr, (const float*)nullptr,
                       (ushortT*)nullptr, (ushortT*)nullptr, (ushortT*)nullptr,
                       DDIM, 768, 1 | 8 | 16);

    for (int i = 0; i < NDEPTH; ++i) {
        hipLaunchKernelGGL(wconv4_k, dim3(1024), dim3(256), 0, stream,
                           qkv_w + (size_t)i * 3 * DDIM * DDIM, wq_bf, (long)3 * DDIM * DDIM,
                           proj_w + (size_t)i * DDIM * DDIM, wp_bf, (long)DDIM * DDIM,
                           mlp_w1 + (size_t)i * NHID * DDIM, w1_bf, (long)NHID * DDIM,
                           mlp_w2 + (size_t)i * DDIM * NHID, w2_bf, (long)DDIM * NHID);

        hipLaunchKernelGGL(ln_k, dim3(MROWS), dim3(256), 0, stream,
                           t, ln1_s + i * DDIM, ln1_b + i * DDIM, (float*)nullptr, h_bf, (long)DDIM);
        hipLaunchKernelGGL(gemm_bf16_k, dim3((3 * DDIM) / 128, MPAD / 128), dim3(256), 0, stream,
                           h_bf, wq_bf, (const float*)nullptr, (const float*)nullptr,
                           (float*)nullptr, (ushortT*)nullptr, sin_t, cos_t,
                           q_bf, k_bf, v_t, 3 * DDIM, DDIM, 64);
        hipLaunchKernelGGL(fattn_k, dim3(96 * QTILES), dim3(256), 0, stream,
                           q_bf, k_bf, v_t, o_bf);
        hipLaunchKernelGGL(gemm_bf16_k, dim3(DDIM / 128, MPAD / 128), dim3(256), 0, stream,
                           o_bf, wp_bf, proj_b + i * DDIM, t, t, (ushortT*)nullptr,
                           (const float*)nullptr, (const float*)nullptr,
                           (ushortT*)nullptr, (ushortT*)nullptr, (ushortT*)nullptr,
                           DDIM, DDIM, 1 | 2 | 16);
        hipLaunchKernelGGL(ln_k, dim3(MROWS), dim3(256), 0, stream,
                           t, ln2_s + i * DDIM, ln2_b + i * DDIM, (float*)nullptr, h_bf, (long)DDIM);
        hipLaunchKernelGGL(gemm_bf16_k, dim3(NHID / 128, MPAD / 128), dim3(256), 0, stream,
                           h_bf, w1_bf, mlp_b1 + i * NHID, (const float*)nullptr,
                           (float*)nullptr, mlp_bf, (const float*)nullptr, (const float*)nullptr,
                           (ushortT*)nullptr, (ushortT*)nullptr, (ushortT*)nullptr,
                           NHID, DDIM, 1 | 4 | 32);
        hipLaunchKernelGGL(gemm_bf16_k, dim3(DDIM / 128, MPAD / 128), dim3(256), 0, stream,
                           mlp_bf, w2_bf, mlp_b2 + i * DDIM, t, t, (ushortT*)nullptr,
                           (const float*)nullptr, (const float*)nullptr,
                           (ushortT*)nullptr, (ushortT*)nullptr, (ushortT*)nullptr,
                           DDIM, NHID, 1 | 2 | 16);
    }
    hipLaunchKernelGGL(ln_k, dim3(NB), dim3(256), 0, stream,
                       t, norm_s, norm_b, (float*)d_out, (ushortT*)nullptr, (long)NL * DDIM);
}

// Round 5
// 3085.027 us; speedup vs baseline: 14.4731x; 1.2089x over previous
//
#include <hip/hip_runtime.h>
#include <math.h>

#define NB 8
#define DDIM 768
#define NHEAD 12
#define NDEPTH 12
#define HDIM 64
#define GRIDW 24
#define NL0 576
#define NL 577
#define LPAD 640
#define NHID 3072
#define MROWS (NB*NL)     // 4616
#define MPAD 4736         // 37*128, 74*64
#define EPSV 1e-5f
#define QTILES 10

typedef unsigned short ushortT;
typedef __attribute__((ext_vector_type(8))) short bf16x8;
typedef __attribute__((ext_vector_type(4))) float f32x4;

__device__ __forceinline__ ushortT f2b(float f) {
    union { float f; unsigned u; } x; x.f = f;
    unsigned r = x.u + 0x7fffu + ((x.u >> 16) & 1u);
    return (ushortT)(r >> 16);
}

__device__ __forceinline__ void load_lds16(const void* g, void* l) {
    __builtin_amdgcn_global_load_lds((const __attribute__((address_space(1))) void*)g,
                                     (__attribute__((address_space(3))) void*)l, 16, 0, 0);
}

// ---------------- fp32 -> bf16 convert ----------------
__global__ void f2b_k(const float* __restrict__ in, ushortT* __restrict__ out, long n) {
    for (long i = ((long)blockIdx.x * 256 + threadIdx.x) * 4; i < n; i += (long)gridDim.x * 1024) {
        float4 v = *(const float4*)(in + i);
        ushort4 o; o.x = f2b(v.x); o.y = f2b(v.y); o.z = f2b(v.z); o.w = f2b(v.w);
        *(ushort4*)(out + i) = o;
    }
}

// ---------------- per-layer 4-weight convert, one launch ----------------
__global__ void wconv4_k(const float* __restrict__ a, ushortT* __restrict__ ao, long na,
                         const float* __restrict__ b, ushortT* __restrict__ bo, long nb,
                         const float* __restrict__ c, ushortT* __restrict__ co, long nc,
                         const float* __restrict__ d, ushortT* __restrict__ dd, long nd) {
    long stride = (long)gridDim.x * 1024;
    long i0 = ((long)blockIdx.x * 256 + threadIdx.x) * 4;
    for (long i = i0; i < na; i += stride) {
        float4 v = *(const float4*)(a + i);
        ushort4 o; o.x = f2b(v.x); o.y = f2b(v.y); o.z = f2b(v.z); o.w = f2b(v.w);
        *(ushort4*)(ao + i) = o;
    }
    for (long i = i0; i < nb; i += stride) {
        float4 v = *(const float4*)(b + i);
        ushort4 o; o.x = f2b(v.x); o.y = f2b(v.y); o.z = f2b(v.z); o.w = f2b(v.w);
        *(ushort4*)(bo + i) = o;
    }
    for (long i = i0; i < nc; i += stride) {
        float4 v = *(const float4*)(c + i);
        ushort4 o; o.x = f2b(v.x); o.y = f2b(v.y); o.z = f2b(v.z); o.w = f2b(v.w);
        *(ushort4*)(co + i) = o;
    }
    for (long i = i0; i < nd; i += stride) {
        float4 v = *(const float4*)(d + i);
        ushort4 o; o.x = f2b(v.x); o.y = f2b(v.y); o.z = f2b(v.z); o.w = f2b(v.w);
        *(ushort4*)(dd + i) = o;
    }
}

// ---------------- im2col -> bf16 patches[4608, 768] ----------------
__global__ void im2col_k(const float* __restrict__ x, ushortT* __restrict__ p) {
    for (long idx = (long)blockIdx.x * 256 + threadIdx.x; idx < (long)4608 * 768; idx += (long)gridDim.x * 256) {
        int row = (int)(idx / 768), col = (int)(idx - (long)row * 768);
        int b = row / NL0, pi = row - b * NL0;
        int gy = pi / GRIDW, gx = pi - gy * GRIDW;
        int c = col >> 8, r = col & 255;
        int py = r >> 4, px = r & 15;
        p[idx] = f2b(x[(((long)(b * 3 + c) * 384) + gy * 16 + py) * 384 + gx * 16 + px]);
    }
}

__global__ void cls_k(const float* __restrict__ cls, float* __restrict__ t) {
    t[(long)blockIdx.x * NL * DDIM + threadIdx.x] = cls[threadIdx.x];
}

__global__ void rope_k(float* __restrict__ sin_t, float* __restrict__ cos_t) {
    int pos = blockIdx.x, d = threadIdx.x;
    int gy = pos / GRIDW, gx = pos - gy * GRIDW;
    int j = d >> 1;
    float ang;
    if (j < 16) ang = (float)gy * powf(10000.f, -(float)j / 16.f);
    else        ang = (float)gx * powf(10000.f, -(float)(j - 16) / 16.f);
    sin_t[pos * 64 + d] = sinf(ang);
    cos_t[pos * 64 + d] = cosf(ang);
}

// ---------------- LayerNorm ----------------
__global__ __launch_bounds__(256) void ln_k(const float* __restrict__ in,
                                            const float* __restrict__ sc,
                                            const float* __restrict__ bi,
                                            float* __restrict__ outf,
                                            ushortT* __restrict__ outb,
                                            long in_rstride) {
    int row = blockIdx.x;
    const float* ip = in + (long)row * in_rstride;
    float x[3];
    float s = 0.f, s2 = 0.f;
    #pragma unroll
    for (int i = 0; i < 3; ++i) {
        x[i] = ip[threadIdx.x + i * 256];
        s += x[i]; s2 += x[i] * x[i];
    }
    __shared__ float red0[256], red1[256];
    red0[threadIdx.x] = s; red1[threadIdx.x] = s2;
    __syncthreads();
    for (int off = 128; off; off >>= 1) {
        if (threadIdx.x < off) {
            red0[threadIdx.x] += red0[threadIdx.x + off];
            red1[threadIdx.x] += red1[threadIdx.x + off];
        }
        __syncthreads();
    }
    float mean = red0[0] * (1.f / 768.f);
    float var  = red1[0] * (1.f / 768.f) - mean * mean;
    float inv = rsqrtf(var + EPSV);
    #pragma unroll
    for (int i = 0; i < 3; ++i) {
        int c = threadIdx.x + i * 256;
        float val = (x[i] - mean) * inv * sc[c] + bi[c];
        if (outb) outb[(long)row * 768 + c] = f2b(val);
        else      outf[(long)row * 768 + c] = val;
    }
}

// ---------------- templated bf16 MFMA GEMM: C[M,N] = A[M,K] @ W[N,K]^T ----------------
// Tile: BM = WR*MI*16 rows, BN = WC*NI*16 cols; 4 waves (WR*WC == 4); BK = 64.
// Double-buffered LDS, 2-phase pipeline: stage(t+1) issued BEFORE compute(t);
// one raw s_barrier + vmcnt(0) per K-step (T3-minimum recipe).
// T2 XOR swizzle: linear global_load_lds dest + inverse-swizzled source; fragment
// reads apply the same involution. T1 bijective XCD chunking on (x,y).
// flags: 1=bias 2=resid(f32) 4=gelu 8=remap(576->577) 16=store f32 32=store bf16
//        64=qkv mode (RoPE + scale + scatter; variant A only)
// SPLITK>1: blockIdx.z selects K-chunk; raw acc written to psum[z][MPAD][N].
template<int WR, int WC, int MI, int NI, int SPLITK>
__global__ __launch_bounds__(256) void gemm_t(const ushortT* __restrict__ A,
                                              const ushortT* __restrict__ W,
                                              const float* __restrict__ bias,
                                              const float* __restrict__ resid,
                                              float* __restrict__ Cf,
                                              ushortT* __restrict__ Cb,
                                              const float* __restrict__ sinT,
                                              const float* __restrict__ cosT,
                                              ushortT* __restrict__ qo,
                                              ushortT* __restrict__ ko,
                                              ushortT* __restrict__ vo,
                                              float* __restrict__ psum,
                                              int N, int K, int flags) {
    constexpr int BM = WR * MI * 16;
    constexpr int BN = WC * NI * 16;
    constexpr int ACH = BM / 32;   // 16B chunks per thread for A tile
    constexpr int BCH = BN / 32;
    __shared__ ushortT As[2][BM * 64];
    __shared__ ushortT Bs[2][BN * 64];
    int tid = threadIdx.x;
    int lane = tid & 63, wid = tid >> 6;
    int wm = wid / WC, wn = wid % WC;
    int lr = lane & 15, lk = lane >> 4;
    // T1: bijective XCD chunking on the (x,y) grid
    int nwg = gridDim.x * gridDim.y;
    int flat = blockIdx.y * gridDim.x + blockIdx.x;
    int qq = nwg >> 3, rr = nwg & 7;
    int xcd = flat & 7, idx = flat >> 3;
    int wg = (xcd < rr ? xcd * (qq + 1) : rr * (qq + 1) + (xcd - rr) * qq) + idx;
    int bx = wg % gridDim.x, by = wg / gridDim.x;
    int m0 = by * BM, n0 = bx * BN;
    int kspan = K / SPLITK;
    int k0 = (SPLITK > 1) ? blockIdx.z * kspan : 0;
    f32x4 acc[MI][NI] = {};

    auto stage = [&](int buf, int kt) {
        #pragma unroll
        for (int i = 0; i < ACH; ++i) {
            int ch = i * 256 + tid;
            int r = ch >> 3, cb = (ch & 7) * 16;
            int cbs = cb ^ ((r & 7) << 4);
            load_lds16(A + (size_t)(m0 + r) * K + kt + (cbs >> 1), &As[buf][ch * 8]);
        }
        #pragma unroll
        for (int i = 0; i < BCH; ++i) {
            int ch = i * 256 + tid;
            int r = ch >> 3, cb = (ch & 7) * 16;
            int cbs = cb ^ ((r & 7) << 4);
            load_lds16(W + (size_t)(n0 + r) * K + kt + (cbs >> 1), &Bs[buf][ch * 8]);
        }
    };

    stage(0, k0);
    asm volatile("s_waitcnt vmcnt(0)" ::: "memory");
    __builtin_amdgcn_s_barrier();
    int nk = kspan / 64;
    int cur = 0;
    for (int it = 0; it < nk; ++it) {
        if (it + 1 < nk) stage(cur ^ 1, k0 + (it + 1) * 64);
        #pragma unroll
        for (int ks = 0; ks < 2; ++ks) {
            bf16x8 aF[MI], bF[NI];
            #pragma unroll
            for (int mi = 0; mi < MI; ++mi) {
                int row = wm * MI * 16 + mi * 16 + lr;
                aF[mi] = *(const bf16x8*)((const char*)&As[cur][0] + row * 128 +
                                          ((ks * 64 + lk * 16) ^ ((row & 7) << 4)));
            }
            #pragma unroll
            for (int ni = 0; ni < NI; ++ni) {
                int row = wn * NI * 16 + ni * 16 + lr;
                bF[ni] = *(const bf16x8*)((const char*)&Bs[cur][0] + row * 128 +
                                          ((ks * 64 + lk * 16) ^ ((row & 7) << 4)));
            }
            #pragma unroll
            for (int mi = 0; mi < MI; ++mi)
                #pragma unroll
                for (int ni = 0; ni < NI; ++ni)
                    acc[mi][ni] = __builtin_amdgcn_mfma_f32_16x16x32_bf16(aF[mi], bF[ni], acc[mi][ni], 0, 0, 0);
        }
        asm volatile("s_waitcnt vmcnt(0)" ::: "memory");
        __builtin_amdgcn_s_barrier();
        cur ^= 1;
    }

    if (SPLITK > 1) {
        // raw partial store (bias/resid applied in reduce kernel)
        #pragma unroll
        for (int mi = 0; mi < MI; ++mi) {
            int rbase = m0 + wm * MI * 16 + mi * 16 + (lane >> 4) * 4;
            #pragma unroll
            for (int ni = 0; ni < NI; ++ni) {
                int c = n0 + wn * NI * 16 + ni * 16 + lr;
                #pragma unroll
                for (int r = 0; r < 4; ++r)
                    psum[((size_t)blockIdx.z * MPAD + rbase + r) * N + c] = acc[mi][ni][r];
            }
        }
        return;
    }
    if (flags & 64) {
        if constexpr (WR == 2 && NI == 4) {
            #pragma unroll
            for (int mi = 0; mi < MI; ++mi) {
                #pragma unroll
                for (int r = 0; r < 4; ++r) {
                    int row = m0 + wm * 64 + mi * 16 + (lane >> 4) * 4 + r;
                    if (row >= MROWS) continue;
                    int b = row / NL, l = row - b * NL;
                    #pragma unroll
                    for (int ni = 0; ni < NI; ++ni) {
                        int c = n0 + wn * 64 + ni * 16 + lr;
                        float val = acc[mi][ni][r];
                        int sel = c / DDIM;
                        int cc = c - sel * DDIM;
                        int h = cc >> 6, d = cc & 63;
                        if (sel < 2 && l > 0) {
                            int pos = l - 1;
                            float cs = cosT[pos * 64 + d], sn = sinT[pos * 64 + d];
                            float partner = acc[mi][ni ^ 2][r];
                            float rh = (d < 32) ? -partner : partner;
                            val = val * cs + rh * sn;
                        }
                        int bh = b * NHEAD + h;
                        if (sel == 0)      qo[((long)bh * LPAD + l) * HDIM + d] = f2b(val * 0.125f);
                        else if (sel == 1) ko[((long)bh * LPAD + l) * HDIM + d] = f2b(val);
                        else               vo[((long)bh * HDIM + d) * LPAD + l] = f2b(val);
                    }
                }
            }
        }
        return;
    }
    #pragma unroll
    for (int mi = 0; mi < MI; ++mi) {
        int rbase = m0 + wm * MI * 16 + mi * 16 + (lane >> 4) * 4;
        #pragma unroll
        for (int ni = 0; ni < NI; ++ni) {
            int c = n0 + wn * NI * 16 + ni * 16 + lr;
            float bv = (flags & 1) ? bias[c] : 0.f;
            #pragma unroll
            for (int r = 0; r < 4; ++r) {
                int row = rbase + r;
                float val = acc[mi][ni][r] + bv;
                if (flags & 4) val = 0.5f * val * (1.f + erff(val * 0.70710678118654752f));
                long orow = row;
                if (flags & 8) orow = (long)(row / NL0) * NL + 1 + (row % NL0);
                if (flags & 2) val += resid[orow * (long)N + c];
                if (flags & 16) Cf[orow * (long)N + c] = val;
                if (flags & 32) Cb[orow * (long)N + c] = f2b(val);
            }
        }
    }
}

// ---------------- split-K reduce for mlp2: t += bias + sum of 4 partials ----------------
__global__ void mlp2red_k(const float* __restrict__ psum, const float* __restrict__ bias,
                          float* __restrict__ t) {
    const long total = (long)MROWS * DDIM;
    const size_t S = (size_t)MPAD * DDIM;
    for (long e = ((long)blockIdx.x * 256 + threadIdx.x) * 4; e < total; e += (long)gridDim.x * 1024) {
        float4 s0 = *(const float4*)(psum + e);
        float4 s1 = *(const float4*)(psum + S + e);
        float4 s2 = *(const float4*)(psum + 2 * S + e);
        float4 s3 = *(const float4*)(psum + 3 * S + e);
        float4 tv = *(const float4*)(t + e);
        int c = (int)(e % DDIM);
        float4 bv = *(const float4*)(bias + c);
        tv.x += bv.x + s0.x + s1.x + s2.x + s3.x;
        tv.y += bv.y + s0.y + s1.y + s2.y + s3.y;
        tv.z += bv.z + s0.z + s1.z + s2.z + s3.z;
        tv.w += bv.w + s0.w + s1.w + s2.w + s3.w;
        *(float4*)(t + e) = tv;
    }
}

// ---------------- MFMA flash attention (unchanged) ----------------
__global__ __launch_bounds__(256) void fattn_k(const ushortT* __restrict__ q,
                                               const ushortT* __restrict__ k,
                                               const ushortT* __restrict__ vt,
                                               ushortT* __restrict__ o) {
    __shared__ ushortT Qs[4096], Ks[4096], Vs[4096], Ps[4096];
    int tid = threadIdx.x;
    int wave = tid >> 6, lane = tid & 63;
    int lr = lane & 15, lk = lane >> 4, g = lk;
    int bh = blockIdx.x / QTILES, qt = blockIdx.x % QTILES;
    int q0 = qt * 64;
    int b = bh / NHEAD, h = bh - b * NHEAD;
    int l8 = lane >> 3, c16 = lane & 7;
    int colsw = (c16 * 16) ^ ((l8 & 7) << 4);

    {
        const ushortT* src = q + ((long)bh * LPAD + q0) * HDIM;
        #pragma unroll
        for (int j = 0; j < 2; ++j) {
            int row = wave * 16 + j * 8 + l8;
            load_lds16(src + (long)row * HDIM + (colsw >> 1), Qs + wave * 1024 + j * 512);
        }
    }
    __syncthreads();
    bf16x8 qF[2];
    #pragma unroll
    for (int ks = 0; ks < 2; ++ks) {
        int row = wave * 16 + lr;
        qF[ks] = *(const bf16x8*)((const char*)Qs + row * 128 + ((ks * 64 + lk * 16) ^ ((lr & 7) << 4)));
    }
    f32x4 oa[4] = {};
    float m_r[4], l_r[4];
    #pragma unroll
    for (int r = 0; r < 4; ++r) { m_r[r] = -3e38f; l_r[r] = 0.f; }

    for (int t0 = 0; t0 < QTILES; ++t0) {
        int k0 = t0 * 64;
        __syncthreads();
        {
            const ushortT* srck = k + ((long)bh * LPAD + k0) * HDIM;
            const ushortT* srcv = vt + (long)bh * HDIM * LPAD + k0;
            #pragma unroll
            for (int j = 0; j < 2; ++j) {
                int row = wave * 16 + j * 8 + l8;
                load_lds16(srck + (long)row * HDIM + (colsw >> 1), Ks + wave * 1024 + j * 512);
                load_lds16(srcv + (long)row * LPAD + (colsw >> 1), Vs + wave * 1024 + j * 512);
            }
        }
        __syncthreads();
        f32x4 s[4] = {};
        #pragma unroll
        for (int ks = 0; ks < 2; ++ks) {
            #pragma unroll
            for (int kt = 0; kt < 4; ++kt) {
                int row = kt * 16 + lr;
                bf16x8 kF = *(const bf16x8*)((const char*)Ks + row * 128 + ((ks * 64 + lk * 16) ^ ((lr & 7) << 4)));
                s[kt] = __builtin_amdgcn_mfma_f32_16x16x32_bf16(qF[ks], kF, s[kt], 0, 0, 0);
            }
        }
        if (k0 + 63 > 576) {
            #pragma unroll
            for (int kt = 0; kt < 4; ++kt)
                if (k0 + kt * 16 + lr > 576) {
                    #pragma unroll
                    for (int r = 0; r < 4; ++r) s[kt][r] = -3e38f;
                }
        }
        float mx[4], al[4], rs[4];
        #pragma unroll
        for (int r = 0; r < 4; ++r)
            mx[r] = fmaxf(fmaxf(s[0][r], s[1][r]), fmaxf(s[2][r], s[3][r]));
        #pragma unroll
        for (int off = 1; off < 16; off <<= 1) {
            #pragma unroll
            for (int r = 0; r < 4; ++r) mx[r] = fmaxf(mx[r], __shfl_xor(mx[r], off));
        }
        #pragma unroll
        for (int r = 0; r < 4; ++r) {
            float mn = fmaxf(m_r[r], mx[r]);
            al[r] = __expf(m_r[r] - mn);
            m_r[r] = mn;
            rs[r] = 0.f;
        }
        #pragma unroll
        for (int kt = 0; kt < 4; ++kt) {
            #pragma unroll
            for (int r = 0; r < 4; ++r) {
                float p = __expf(s[kt][r] - m_r[r]);
                rs[r] += p;
                int rowp = g * 4 + r;
                *(ushortT*)((char*)Ps + wave * 2048 + rowp * 128 +
                            ((kt * 32 + lr * 2) ^ ((rowp & 7) << 4))) = f2b(p);
            }
        }
        #pragma unroll
        for (int off = 1; off < 16; off <<= 1) {
            #pragma unroll
            for (int r = 0; r < 4; ++r) rs[r] += __shfl_xor(rs[r], off);
        }
        #pragma unroll
        for (int r = 0; r < 4; ++r) l_r[r] = l_r[r] * al[r] + rs[r];
        #pragma unroll
        for (int dt = 0; dt < 4; ++dt) {
            #pragma unroll
            for (int r = 0; r < 4; ++r) oa[dt][r] *= al[r];
        }
        __syncthreads();
        #pragma unroll
        for (int ks = 0; ks < 2; ++ks) {
            bf16x8 pA = *(const bf16x8*)((const char*)Ps + wave * 2048 + lr * 128 +
                                         ((ks * 64 + lk * 16) ^ ((lr & 7) << 4)));
            #pragma unroll
            for (int dt = 0; dt < 4; ++dt) {
                bf16x8 vF = *(const bf16x8*)((const char*)Vs + (dt * 16 + lr) * 128 +
                                             ((ks * 64 + lk * 16) ^ ((lr & 7) << 4)));
                oa[dt] = __builtin_amdgcn_mfma_f32_16x16x32_bf16(pA, vF, oa[dt], 0, 0, 0);
            }
        }
    }
    #pragma unroll
    for (int r = 0; r < 4; ++r) {
        int l = q0 + wave * 16 + g * 4 + r;
        if (l > 576) continue;
        float inv = 1.f / l_r[r];
        #pragma unroll
        for (int dt = 0; dt < 4; ++dt)
            o[((long)(b * NL + l)) * DDIM + h * HDIM + dt * 16 + lr] = f2b(oa[dt][r] * inv);
    }
}

extern "C" void kernel_launch(void* const* d_in, const int* in_sizes, int n_in,
                              void* d_out, int out_size, void* d_ws, size_t ws_size,
                              hipStream_t stream) {
    const float* x       = (const float*)d_in[0];
    const float* patch_w = (const float*)d_in[1];
    const float* patch_b = (const float*)d_in[2];
    const float* cls     = (const float*)d_in[3];
    const float* ln1_s   = (const float*)d_in[4];
    const float* ln1_b   = (const float*)d_in[5];
    const float* qkv_w   = (const float*)d_in[6];
    const float* proj_w  = (const float*)d_in[7];
    const float* proj_b  = (const float*)d_in[8];
    const float* ln2_s   = (const float*)d_in[9];
    const float* ln2_b   = (const float*)d_in[10];
    const float* mlp_w1  = (const float*)d_in[11];
    const float* mlp_b1  = (const float*)d_in[12];
    const float* mlp_w2  = (const float*)d_in[13];
    const float* mlp_b2  = (const float*)d_in[14];
    const float* norm_s  = (const float*)d_in[15];
    const float* norm_b  = (const float*)d_in[16];

    char* w = (char*)d_ws;
    float* t      = (float*)w;  w += (size_t)MPAD * DDIM * 4;
    float* sin_t  = (float*)w;  w += (size_t)NL0 * HDIM * 4;
    float* cos_t  = (float*)w;  w += (size_t)NL0 * HDIM * 4;
    float* psum   = (float*)w;  w += (size_t)4 * MPAD * DDIM * 4;
    ushortT* h_bf   = (ushortT*)w; w += (size_t)MPAD * DDIM * 2;
    ushortT* o_bf   = (ushortT*)w; w += (size_t)MPAD * DDIM * 2;
    ushortT* mlp_bf = (ushortT*)w; w += (size_t)MPAD * NHID * 2;
    ushortT* patches = mlp_bf;    // alias: disjoint lifetime (pre-loop only)
    ushortT* q_bf   = (ushortT*)w; w += (size_t)96 * LPAD * HDIM * 2;
    ushortT* k_bf   = (ushortT*)w; w += (size_t)96 * LPAD * HDIM * 2;
    ushortT* v_t    = (ushortT*)w; w += (size_t)96 * HDIM * LPAD * 2;
    ushortT* pw_bf  = (ushortT*)w; w += (size_t)DDIM * 768 * 2;
    ushortT* wq_bf  = (ushortT*)w; w += (size_t)3 * DDIM * DDIM * 2;
    ushortT* wp_bf  = (ushortT*)w; w += (size_t)DDIM * DDIM * 2;
    ushortT* w1_bf  = (ushortT*)w; w += (size_t)NHID * DDIM * 2;
    ushortT* w2_bf  = (ushortT*)w; w += (size_t)DDIM * NHID * 2;

    const float* nfp = nullptr;
    ushortT* nus = nullptr;
    float* nf = nullptr;

    hipLaunchKernelGGL(rope_k, dim3(NL0), dim3(64), 0, stream, sin_t, cos_t);
    hipLaunchKernelGGL(im2col_k, dim3(2048), dim3(256), 0, stream, x, patches);
    hipLaunchKernelGGL(f2b_k, dim3(512), dim3(256), 0, stream, patch_w, pw_bf, (long)DDIM * 768);
    hipLaunchKernelGGL(cls_k, dim3(NB), dim3(DDIM), 0, stream, cls, t);
    // patch embed: 64x128 tile variant, grid 6x72
    hipLaunchKernelGGL((gemm_t<1, 4, 4, 2, 1>), dim3(DDIM / 128, 4608 / 64), dim3(256), 0, stream,
                       patches, pw_bf, patch_b, nfp, t, nus, nfp, nfp, nus, nus, nus, nf,
                       DDIM, 768, 1 | 8 | 16);

    for (int i = 0; i < NDEPTH; ++i) {
        hipLaunchKernelGGL(wconv4_k, dim3(1024), dim3(256), 0, stream,
                           qkv_w + (size_t)i * 3 * DDIM * DDIM, wq_bf, (long)3 * DDIM * DDIM,
                           proj_w + (size_t)i * DDIM * DDIM, wp_bf, (long)DDIM * DDIM,
                           mlp_w1 + (size_t)i * NHID * DDIM, w1_bf, (long)NHID * DDIM,
                           mlp_w2 + (size_t)i * DDIM * NHID, w2_bf, (long)DDIM * NHID);

        hipLaunchKernelGGL(ln_k, dim3(MROWS), dim3(256), 0, stream,
                           t, ln1_s + i * DDIM, ln1_b + i * DDIM, nf, h_bf, (long)DDIM);
        // QKV GEMM (128x128) with fused RoPE + scatter
        hipLaunchKernelGGL((gemm_t<2, 2, 4, 4, 1>), dim3((3 * DDIM) / 128, MPAD / 128), dim3(256), 0, stream,
                           h_bf, wq_bf, nfp, nfp, nf, nus, sin_t, cos_t,
                           q_bf, k_bf, v_t, nf, 3 * DDIM, DDIM, 64);
        hipLaunchKernelGGL(fattn_k, dim3(96 * QTILES), dim3(256), 0, stream,
                           q_bf, k_bf, v_t, o_bf);
        // proj: 64x128 tile variant, grid 6x74
        hipLaunchKernelGGL((gemm_t<1, 4, 4, 2, 1>), dim3(DDIM / 128, MPAD / 64), dim3(256), 0, stream,
                           o_bf, wp_bf, proj_b + i * DDIM, t, t, nus, nfp, nfp, nus, nus, nus, nf,
                           DDIM, DDIM, 1 | 2 | 16);
        hipLaunchKernelGGL(ln_k, dim3(MROWS), dim3(256), 0, stream,
                           t, ln2_s + i * DDIM, ln2_b + i * DDIM, nf, h_bf, (long)DDIM);
        // mlp1: 128x128
        hipLaunchKernelGGL((gemm_t<2, 2, 4, 4, 1>), dim3(NHID / 128, MPAD / 128), dim3(256), 0, stream,
                           h_bf, w1_bf, mlp_b1 + i * NHID, nfp, nf, mlp_bf, nfp, nfp,
                           nus, nus, nus, nf, NHID, DDIM, 1 | 4 | 32);
        // mlp2: split-K 4 partials, then fused reduce(bias+resid)
        hipLaunchKernelGGL((gemm_t<2, 2, 4, 4, 4>), dim3(DDIM / 128, MPAD / 128, 4), dim3(256), 0, stream,
                           mlp_bf, w2_bf, nfp, nfp, nf, nus, nfp, nfp,
                           nus, nus, nus, psum, DDIM, NHID, 0);
        hipLaunchKernelGGL(mlp2red_k, dim3(2048), dim3(256), 0, stream,
                           psum, mlp_b2 + i * DDIM, t);
    }
    hipLaunchKernelGGL(ln_k, dim3(NB), dim3(256), 0, stream,
                       t, norm_s, norm_b, (float*)d_out, nus, (long)NL * DDIM);
}